// Round 5
// baseline (636.426 us; speedup 1.0000x reference)
//
#include <hip/hip_runtime.h>
#include <stdint.h>

// Problem constants
#define B_    8
#define T_    4096
#define HID   512
#define SD    256
#define NH    8
#define HD    32
#define M_TOK (B_*T_)          // 32768 tokens
#define NPROJ 1536             // 6 * 256 output channels (k,v,q,beta,alpha,gate)

typedef __attribute__((ext_vector_type(8))) short short8;   // 8 bf16 (4 VGPRs) — MFMA A/B frag
typedef __attribute__((ext_vector_type(4))) float f32x4;    // MFMA C/D frag
typedef __attribute__((ext_vector_type(4))) float f4;       // asm ds_read_b128 dst
typedef __attribute__((ext_vector_type(2))) float f2;       // packed fp32 (v_pk_*_f32)

__device__ __forceinline__ unsigned short f2bf(float f) {
  uint32_t u = __float_as_uint(f);
  uint32_t r = (u + 0x7fffu + ((u >> 16) & 1u)) >> 16;
  return (unsigned short)r;
}

__device__ __forceinline__ void gload16(const void* g, void* l) {
  // async global->LDS, 16B per lane; LDS dest = wave-uniform base + lane*16
  __builtin_amdgcn_global_load_lds((const __attribute__((address_space(1))) void*)g,
                                   (__attribute__((address_space(3))) void*)l,
                                   16, 0, 0);
}

// butterfly sum across the 4 lanes of a quad — pure VALU (DPP), no DS pipe
__device__ __forceinline__ float qred(float x) {
  x += __int_as_float(__builtin_amdgcn_mov_dpp(__float_as_int(x), 0xB1, 0xF, 0xF, true)); // lane^1
  x += __int_as_float(__builtin_amdgcn_mov_dpp(__float_as_int(x), 0x4E, 0xF, 0xF, true)); // lane^2
  return x;
}

// ---------------------------------------------------------------- converts
__global__ void cvt_f32_bf16(const float* __restrict__ in, unsigned short* __restrict__ out, int n4) {
  int i = blockIdx.x * blockDim.x + threadIdx.x;
  int stride = gridDim.x * blockDim.x;
  for (; i < n4; i += stride) {
    float4 v = reinterpret_cast<const float4*>(in)[i];
    ushort4 o;
    o.x = f2bf(v.x); o.y = f2bf(v.y); o.z = f2bf(v.z); o.w = f2bf(v.w);
    reinterpret_cast<ushort4*>(out)[i] = o;
  }
}

// ---------------------------------------------------------------- projection GEMM
#define PM 128
#define PN 64
#define PK 64

__global__ void __launch_bounds__(256) proj_gemm(
    const unsigned short* __restrict__ hb, const unsigned short* __restrict__ Wc,
    const float* __restrict__ b_beta, const float* __restrict__ b_alpha,
    float* __restrict__ Kp, float* __restrict__ Qp,
    float* __restrict__ AVBf, float* __restrict__ gate)
{
  __shared__ unsigned short Asm[PM*PK];  // 16 KB
  __shared__ unsigned short Bsm[PN*PK];  // 8 KB
  const int t = threadIdx.x;
  const int w = t >> 6, lane = t & 63;
  const int bm0 = blockIdx.x * PM;
  const int bn0 = blockIdx.y * PN;

  f32x4 acc[2][4];
  #pragma unroll
  for (int i = 0; i < 2; ++i)
    #pragma unroll
    for (int j = 0; j < 4; ++j) acc[i][j] = (f32x4){0.f, 0.f, 0.f, 0.f};

  for (int k0 = 0; k0 < HID; k0 += PK) {
    #pragma unroll
    for (int it = 0; it < 4; ++it) {
      int unit = t + it * 256;
      int row = unit >> 3, seg = unit & 7;
      int dseg = seg ^ (row & 7);
      const unsigned short* g = hb + (size_t)(bm0 + row) * HID + k0 + dseg * 8;
      gload16(g, (char*)Asm + (w * 1024 + it * 4096));
    }
    #pragma unroll
    for (int it = 0; it < 2; ++it) {
      int unit = t + it * 256;
      int n = unit >> 3, seg = unit & 7;
      int dseg = seg ^ (n & 7);
      const unsigned short* g = Wc + (size_t)(bn0 + n) * HID + k0 + dseg * 8;
      gload16(g, (char*)Bsm + (w * 1024 + it * 4096));
    }
    __syncthreads();
    #pragma unroll
    for (int ks = 0; ks < 2; ++ks) {
      short8 af[2], bfr[4];
      int u = ks * 4 + (lane >> 4);
      int slot = u ^ (lane & 7);
      #pragma unroll
      for (int rb = 0; rb < 2; ++rb) {
        int row = w * 32 + rb * 16 + (lane & 15);
        af[rb] = *(const short8*)((const char*)Asm + row * 128 + slot * 16);
      }
      #pragma unroll
      for (int cb = 0; cb < 4; ++cb) {
        int nn = cb * 16 + (lane & 15);
        bfr[cb] = *(const short8*)((const char*)Bsm + nn * 128 + slot * 16);
      }
      #pragma unroll
      for (int rb = 0; rb < 2; ++rb)
        #pragma unroll
        for (int cb = 0; cb < 4; ++cb)
          acc[rb][cb] = __builtin_amdgcn_mfma_f32_16x16x32_bf16(af[rb], bfr[cb], acc[rb][cb], 0, 0, 0);
    }
    __syncthreads();
  }

  const int p = bn0 >> 8;   // 0:k 1:v 2:q 3:beta 4:alpha 5:gate
  #pragma unroll
  for (int rb = 0; rb < 2; ++rb) {
    #pragma unroll
    for (int cb = 0; cb < 4; ++cb) {
      int n = bn0 + cb * 16 + (lane & 15);
      int rem = n & 255;
      #pragma unroll
      for (int r = 0; r < 4; ++r) {
        int m = bm0 + w * 32 + rb * 16 + (lane >> 4) * 4 + r;
        float v = acc[rb][cb][r];
        int b = m >> 12, tt = m & 4095;
        int h = rem >> 5, d = rem & 31;
        size_t tok = ((size_t)(b * NH + h) * T_ + tt);
        if (p == 0) {
          Kp[tok * HD + d] = v;
        } else if (p == 2) {
          Qp[tok * HD + d] = v;
        } else if (p == 5) {
          gate[(size_t)m * SD + rem] = v;
        } else {
          float wv = v;
          if (p == 3) wv = 1.0f / (1.0f + expf(-(v + b_beta[rem])));
          if (p == 4) wv = 1.0f / (1.0f + expf(-(v + b_alpha[rem])));
          int comp = (p == 4) ? 0 : (p == 1) ? 1 : 2;   // (a, v, beta, pad)
          AVBf[(tok * HD + d) * 4 + comp] = wv;
        }
      }
    }
  }
}

// ---------------------------------------------------------------- k normalization
__global__ void __launch_bounds__(256) knorm(float* __restrict__ Kp) {
  int t = threadIdx.x;
  size_t row = (size_t)blockIdx.x * 8 + (t >> 5);
  int j = t & 31;
  float x = Kp[row * 32 + j];
  float s = x * x;
  #pragma unroll
  for (int m = 16; m >= 1; m >>= 1) s += __shfl_xor(s, m, 32);
  float inv = 1.0f / fmaxf(sqrtf(s), 1e-12f);
  Kp[row * 32 + j] = x * inv;
}

// ---------------------------------------------------------------- sequential scan
// 128 blocks x 64 threads; lane l: row i = half*16 + (l>>2), part p = l&3 (8 cols).
// Depth-4 register pipeline: 4 named sets (A..D), each staged by 5 asm
// ds_read_b128 issued 4 steps ahead of use (~280cy cover >= ~240cy LDS
// round-trip). Each consume-wait is s_waitcnt lgkmcnt(N) that formally WRITES
// the set's registers (precise dep, rule-#18-safe, no global fences).
// Chunk (32 steps) staged via global_load_lds one chunk ahead; counted
// vmcnt(32) = 8 group-stores + 24 prefetch loads.
// LDS layout: K[2][4KB] @0, Q[2][4KB] @8192, V(avb)[2][16KB] @16384 (48KB).
#define CH 32
#define NCH (T_/CH)

#define DSR(dst, areg, imm) \
  asm volatile("ds_read_b128 %0, %1 offset:%c2" : "=v"(dst) : "v"(areg), "i"(imm))

#define SHUF2(V,A,B) __builtin_shufflevector(V, V, A, B)

__global__ void __launch_bounds__(64, 1) scan_kernel(
    const float* __restrict__ Kp, const float* __restrict__ Qp,
    const float4* __restrict__ AVB, const float* __restrict__ state_in,
    float* __restrict__ ctx, float* __restrict__ Sfin)
{
  __shared__ __align__(16) char Lds[49152];
  const int bk = blockIdx.x;
  const int bh = bk >> 1, half = bk & 1;
  const int b = bh >> 3, h = bh & 7;
  const int l = threadIdx.x;
  const int i = half * 16 + (l >> 2);   // state row
  const int p = l & 3;                  // column part
  const bool isP0 = (p == 0), isP1 = (p == 1), isP2 = (p == 2), isP3 = (p == 3);

  const float*  Kg = Kp  + (size_t)bh * (T_ * HD);
  const float*  Qg = Qp  + (size_t)bh * (T_ * HD);
  const float4* Vg = AVB + (size_t)bh * (T_ * HD);

  f2 S01, S23, S45, S67;
  {
    const float* sp = state_in + (size_t)bh * 1024 + i * 32 + p * 8;
    float4 s0 = *(const float4*)sp, s1 = *(const float4*)(sp + 4);
    S01 = (f2){s0.x, s0.y}; S23 = (f2){s0.z, s0.w};
    S45 = (f2){s1.x, s1.y}; S67 = (f2){s1.z, s1.w};
  }

  float* ctxq = ctx + (size_t)b * T_ * SD + h * HD + i + (size_t)p * SD;
  float osel = 0.0f;

  const uint32_t lds0 = (uint32_t)(uintptr_t)(__attribute__((address_space(3))) char*)&Lds[0];
  const uint32_t a_kq = lds0 + p * 32;   // per-lane K/Q fragment base
  const uint32_t a_v  = lds0 + i * 16;   // per-lane AVB base

  auto stage = [&](int c2, int buf) {
    const float*  kg = Kg + (size_t)c2 * (CH * HD);
    const float*  qg = Qg + (size_t)c2 * (CH * HD);
    const float4* vg = Vg + (size_t)c2 * (CH * HD);
    #pragma unroll
    for (int it = 0; it < 4; ++it) {
      gload16(kg + (size_t)(l + it * 64) * 4, Lds + buf * 4096 + it * 1024);
      gload16(qg + (size_t)(l + it * 64) * 4, Lds + 8192 + buf * 4096 + it * 1024);
    }
    #pragma unroll
    for (int it = 0; it < 16; ++it) {
      gload16(vg + (l + it * 64), Lds + 16384 + buf * 16384 + it * 1024);
    }
  };

#define DOSTEP(KA,KB,QA,QB,VV,J) do { \
    f2 kl_ = SHUF2(KA,0,1), kh_ = SHUF2(KA,2,3); \
    f2 kl2_ = SHUF2(KB,0,1), kh2_ = SHUF2(KB,2,3); \
    f2 m1_ = kl_*S01, m2_ = kh_*S23, m3_ = kl2_*S45, m4_ = kh2_*S67; \
    f2 hh_ = (m1_+m2_)+(m3_+m4_); \
    float pd_ = qred(hh_.x + hh_.y); \
    float bv_ = VV.y * VV.z, ba_ = VV.x * VV.z; \
    float u_ = fmaf(-ba_, pd_, bv_); \
    f2 A2_ = (f2){VV.x, VV.x}; \
    f2 U2_ = (f2){u_, u_}; \
    S01 = __builtin_elementwise_fma(U2_, kl_,  A2_*S01); \
    S23 = __builtin_elementwise_fma(U2_, kh_,  A2_*S23); \
    S45 = __builtin_elementwise_fma(U2_, kl2_, A2_*S45); \
    S67 = __builtin_elementwise_fma(U2_, kh2_, A2_*S67); \
    f2 o1_ = SHUF2(QA,0,1)*S01, o2_ = SHUF2(QA,2,3)*S23; \
    f2 o3_ = SHUF2(QB,0,1)*S45, o4_ = SHUF2(QB,2,3)*S67; \
    f2 oh_ = (o1_+o2_)+(o3_+o4_); \
    float od_ = qred(oh_.x + oh_.y); \
    const bool sel_ = (J)==0 ? isP0 : (J)==1 ? isP1 : (J)==2 ? isP2 : isP3; \
    osel = sel_ ? od_ : osel; \
  } while (0)

  // 4 pipeline sets x 1 step x 5 frags = 80 VGPR pinned staging
  f4 kaA,kbA,qaA,qbA,vvA;
  f4 kaB,kbB,qaB,qbB,vvB;
  f4 kaC,kbC,qaC,qbC,vvC;
  f4 kaD,kbD,qaD,qbD,vvD;

#define R1(S, BUF, T) do { \
    DSR(ka##S, a_kq, (BUF)*4096 + (T)*128); \
    DSR(kb##S, a_kq, (BUF)*4096 + (T)*128 + 16); \
    DSR(qa##S, a_kq, 8192 + (BUF)*4096 + (T)*128); \
    DSR(qb##S, a_kq, 8192 + (BUF)*4096 + (T)*128 + 16); \
    DSR(vv##S, a_v,  16384 + (BUF)*16384 + (T)*512); \
  } while (0)

// waitcnt that formally WRITES the set's staged registers: consumers are
// data-dependent on the wait, everything else schedules freely (rule #18).
#define WKA(N, S) \
    asm volatile("s_waitcnt lgkmcnt(" #N ")" \
                 : "+v"(ka##S), "+v"(kb##S), "+v"(qa##S), "+v"(qb##S), "+v"(vv##S))

#define C1(S, T) do { \
    DOSTEP(ka##S, kb##S, qa##S, qb##S, vv##S, (T)&3); \
    if (((T)&3) == 3) { *ctxq = osel; ctxq += 4 * SD; } \
  } while (0)

#define CHUNKBODY(BUF) do { \
    if (ci == 0 || ci == NCH-1) { asm volatile("s_waitcnt vmcnt(0)" ::: "memory"); } \
    else                        { asm volatile("s_waitcnt vmcnt(32)" ::: "memory"); } \
    __builtin_amdgcn_sched_barrier(0); \
    R1(A,BUF,0); R1(B,BUF,1); R1(C,BUF,2); R1(D,BUF,3); \
    WKA(15,A); C1(A, 0); R1(A,BUF, 4); \
    WKA(15,B); C1(B, 1); R1(B,BUF, 5); \
    WKA(15,C); C1(C, 2); R1(C,BUF, 6); \
    WKA(15,D); C1(D, 3); R1(D,BUF, 7); \
    WKA(15,A); C1(A, 4); R1(A,BUF, 8); \
    WKA(15,B); C1(B, 5); R1(B,BUF, 9); \
    WKA(15,C); C1(C, 6); R1(C,BUF,10); \
    WKA(15,D); C1(D, 7); R1(D,BUF,11); \
    WKA(15,A); C1(A, 8); R1(A,BUF,12); \
    WKA(15,B); C1(B, 9); R1(B,BUF,13); \
    WKA(15,C); C1(C,10); R1(C,BUF,14); \
    WKA(15,D); C1(D,11); R1(D,BUF,15); \
    WKA(15,A); C1(A,12); R1(A,BUF,16); \
    WKA(15,B); C1(B,13); R1(B,BUF,17); \
    WKA(15,C); C1(C,14); R1(C,BUF,18); \
    WKA(15,D); C1(D,15); R1(D,BUF,19); \
    WKA(15,A); C1(A,16); R1(A,BUF,20); \
    WKA(15,B); C1(B,17); R1(B,BUF,21); \
    WKA(15,C); C1(C,18); R1(C,BUF,22); \
    WKA(15,D); C1(D,19); R1(D,BUF,23); \
    WKA(15,A); C1(A,20); R1(A,BUF,24); \
    WKA(15,B); C1(B,21); R1(B,BUF,25); \
    WKA(15,C); C1(C,22); R1(C,BUF,26); \
    WKA(15,D); C1(D,23); R1(D,BUF,27); \
    WKA(15,A); C1(A,24); R1(A,BUF,28); \
    WKA(15,B); C1(B,25); R1(B,BUF,29); \
    WKA(15,C); C1(C,26); R1(C,BUF,30); \
    WKA(15,D); C1(D,27); R1(D,BUF,31); \
    WKA(15,A); C1(A,28); \
    WKA(10,B); C1(B,29); \
    WKA(5,C);  C1(C,30); \
    WKA(0,D);  C1(D,31); \
    if (ci + 2 < NCH) stage(ci + 2, BUF); \
  } while (0)

  stage(0, 0);
  stage(1, 1);
  int ci;
  #pragma unroll 1
  for (int cp = 0; cp < NCH / 2; ++cp) {
    ci = cp * 2;
    CHUNKBODY(0);
    ci = cp * 2 + 1;
    CHUNKBODY(1);
  }

  {
    float* sp = Sfin + (size_t)bh * 1024 + i * 32 + p * 8;
    sp[0] = S01.x; sp[1] = S01.y; sp[2] = S23.x; sp[3] = S23.y;
    sp[4] = S45.x; sp[5] = S45.y; sp[6] = S67.x; sp[7] = S67.y;
  }
#undef DOSTEP
#undef R1
#undef WKA
#undef C1
#undef CHUNKBODY
}

// ---------------------------------------------------------------- rmsnorm * silu(gate) -> bf16
__global__ void __launch_bounds__(256) rms_silu(
    const float* __restrict__ ctx, const float* __restrict__ gate,
    const float* __restrict__ norm_w, unsigned short* __restrict__ ctx2)
{
  size_t row = (size_t)blockIdx.x * 4 + (threadIdx.x >> 6);
  int lane = threadIdx.x & 63;
  const float4 x = *(const float4*)&ctx[row * SD + lane * 4];
  float s = x.x * x.x + x.y * x.y + x.z * x.z + x.w * x.w;
  #pragma unroll
  for (int m = 32; m >= 1; m >>= 1) s += __shfl_xor(s, m, 64);
  float rs = 1.0f / sqrtf(s * (1.0f / 256.0f) + 1e-6f);
  const float4 g = *(const float4*)&gate[row * SD + lane * 4];
  const float4 w = *(const float4*)&norm_w[lane * 4];
  ushort4 o;
  o.x = f2bf(x.x * rs * w.x * (g.x / (1.0f + expf(-g.x))));
  o.y = f2bf(x.y * rs * w.y * (g.y / (1.0f + expf(-g.y))));
  o.z = f2bf(x.z * rs * w.z * (g.z / (1.0f + expf(-g.z))));
  o.w = f2bf(x.w * rs * w.w * (g.w / (1.0f + expf(-g.w))));
  *(ushort4*)&ctx2[row * SD + lane * 4] = o;
}

// ---------------------------------------------------------------- output GEMM
__global__ void __launch_bounds__(256) out_gemm(
    const unsigned short* __restrict__ ctx2, const unsigned short* __restrict__ Wob,
    float* __restrict__ out)
{
  __shared__ unsigned short Asm[PM*PK];
  __shared__ unsigned short Bsm[PN*PK];
  const int t = threadIdx.x;
  const int w = t >> 6, lane = t & 63;
  const int bm0 = blockIdx.x * PM;
  const int bn0 = blockIdx.y * PN;

  f32x4 acc[2][4];
  #pragma unroll
  for (int i = 0; i < 2; ++i)
    #pragma unroll
    for (int j = 0; j < 4; ++j) acc[i][j] = (f32x4){0.f, 0.f, 0.f, 0.f};

  for (int k0 = 0; k0 < SD; k0 += PK) {
    #pragma unroll
    for (int it = 0; it < 4; ++it) {
      int unit = t + it * 256;
      int row = unit >> 3, seg = unit & 7;
      int dseg = seg ^ (row & 7);
      const unsigned short* g = ctx2 + (size_t)(bm0 + row) * SD + k0 + dseg * 8;
      gload16(g, (char*)Asm + (w * 1024 + it * 4096));
    }
    #pragma unroll
    for (int it = 0; it < 2; ++it) {
      int unit = t + it * 256;
      int n = unit >> 3, seg = unit & 7;
      int dseg = seg ^ (n & 7);
      const unsigned short* g = Wob + (size_t)(bn0 + n) * SD + k0 + dseg * 8;
      gload16(g, (char*)Bsm + (w * 1024 + it * 4096));
    }
    __syncthreads();
    #pragma unroll
    for (int ks = 0; ks < 2; ++ks) {
      short8 af[2], bfr[4];
      int u = ks * 4 + (lane >> 4);
      int slot = u ^ (lane & 7);
      #pragma unroll
      for (int rb = 0; rb < 2; ++rb) {
        int row = w * 32 + rb * 16 + (lane & 15);
        af[rb] = *(const short8*)((const char*)Asm + row * 128 + slot * 16);
      }
      #pragma unroll
      for (int cb = 0; cb < 4; ++cb) {
        int nn = cb * 16 + (lane & 15);
        bfr[cb] = *(const short8*)((const char*)Bsm + nn * 128 + slot * 16);
      }
      #pragma unroll
      for (int rb = 0; rb < 2; ++rb)
        #pragma unroll
        for (int cb = 0; cb < 4; ++cb)
          acc[rb][cb] = __builtin_amdgcn_mfma_f32_16x16x32_bf16(af[rb], bfr[cb], acc[rb][cb], 0, 0, 0);
    }
    __syncthreads();
  }
  #pragma unroll
  for (int rb = 0; rb < 2; ++rb)
    #pragma unroll
    for (int cb = 0; cb < 4; ++cb) {
      int n = bn0 + cb * 16 + (lane & 15);
      #pragma unroll
      for (int r = 0; r < 4; ++r) {
        int m = bm0 + w * 32 + rb * 16 + (lane >> 4) * 4 + r;
        out[(size_t)m * 512 + n] = acc[rb][cb][r];
      }
    }
}

// ---------------------------------------------------------------- launcher
// ws layout (bytes), total 253,493,248:
//   hb   bf16 [32768][512]            @ 0
//   Wc   bf16 [1536][512]             @ 33,554,432
//   Wob  bf16 [512][256]              @ 35,127,296
//   Kp   f32  [64][4096][32]          @ 35,389,440
//   Qp   f32  [64][4096][32]          @ 68,943,872
//   AVB  f32x4 [64][4096][32]         @ 102,498,304   (a, v, beta, pad)
//   ctx2 bf16 [32768][256]            @ 236,716,032
// d_out reuse: ctx f32 [32768][256] @ 0; gate f32 [32768][256] @ +8388608 floats
// (both overwritten later by out_gemm); Sfin @ +16777216 floats.
extern "C" void kernel_launch(void* const* d_in, const int* in_sizes, int n_in,
                              void* d_out, int out_size, void* d_ws, size_t ws_size,
                              hipStream_t stream) {
  (void)in_sizes; (void)n_in; (void)out_size; (void)ws_size;
  const float* hidden  = (const float*)d_in[0];
  const float* state   = (const float*)d_in[1];
  const float* W_k     = (const float*)d_in[2];
  const float* W_v     = (const float*)d_in[3];
  const float* W_q     = (const float*)d_in[4];
  const float* W_beta  = (const float*)d_in[5];
  const float* b_beta  = (const float*)d_in[6];
  const float* W_alpha = (const float*)d_in[7];
  const float* b_alpha = (const float*)d_in[8];
  const float* W_out   = (const float*)d_in[9];
  const float* gate_W  = (const float*)d_in[10];
  const float* norm_w  = (const float*)d_in[11];
  float* out = (float*)d_out;

  char* ws = (char*)d_ws;
  unsigned short* hb  = (unsigned short*)(ws);
  unsigned short* Wc  = (unsigned short*)(ws + 33554432);
  unsigned short* Wob = (unsigned short*)(ws + 35127296);
  float* Kp   = (float*)(ws + 35389440);
  float* Qp   = (float*)(ws + 68943872);
  float* AVBf = (float*)(ws + 102498304);
  unsigned short* ctx2 = (unsigned short*)(ws + 236716032);
  float* ctx  = out;                 // fp32 scratch, overwritten by out_gemm
  float* gate = out + 8388608;       // fp32 scratch, overwritten by out_gemm
  float* Sfin = out + 16777216;      // final state output

  cvt_f32_bf16<<<2048, 256, 0, stream>>>(hidden, hb, M_TOK * HID / 4);
  cvt_f32_bf16<<<64, 256, 0, stream>>>(W_k,     Wc + 0 * 131072, 32768);
  cvt_f32_bf16<<<64, 256, 0, stream>>>(W_v,     Wc + 1 * 131072, 32768);
  cvt_f32_bf16<<<64, 256, 0, stream>>>(W_q,     Wc + 2 * 131072, 32768);
  cvt_f32_bf16<<<64, 256, 0, stream>>>(W_beta,  Wc + 3 * 131072, 32768);
  cvt_f32_bf16<<<64, 256, 0, stream>>>(W_alpha, Wc + 4 * 131072, 32768);
  cvt_f32_bf16<<<64, 256, 0, stream>>>(gate_W,  Wc + 5 * 131072, 32768);
  cvt_f32_bf16<<<64, 256, 0, stream>>>(W_out,   Wob, 32768);

  proj_gemm<<<dim3(256, 24), 256, 0, stream>>>(hb, Wc, b_beta, b_alpha, Kp, Qp, AVBf, gate);
  knorm<<<32768, 256, 0, stream>>>(Kp);
  scan_kernel<<<128, 64, 0, stream>>>(Kp, Qp, (const float4*)AVBf, state, ctx, Sfin);
  rms_silu<<<8192, 256, 0, stream>>>(ctx, gate, norm_w, ctx2);
  out_gemm<<<dim3(256, 8), 256, 0, stream>>>(ctx2, Wob, out);
}

// Round 6
// 604.974 us; speedup vs baseline: 1.0520x; 1.0520x over previous
//
#include <hip/hip_runtime.h>
#include <stdint.h>

// Problem constants
#define B_    8
#define T_    4096
#define HID   512
#define SD    256
#define NH    8
#define HD    32
#define M_TOK (B_*T_)          // 32768 tokens
#define NPROJ 1536             // 6 * 256 output channels (k,v,q,beta,alpha,gate)

typedef __attribute__((ext_vector_type(8))) short short8;   // 8 bf16 (4 VGPRs) — MFMA A/B frag
typedef __attribute__((ext_vector_type(4))) float f32x4;    // MFMA C/D frag
typedef __attribute__((ext_vector_type(4))) float f4;       // asm ds_read_b128 dst
typedef __attribute__((ext_vector_type(2))) float f2;       // packed fp32 (v_pk_*_f32)

__device__ __forceinline__ unsigned short f2bf(float f) {
  uint32_t u = __float_as_uint(f);
  uint32_t r = (u + 0x7fffu + ((u >> 16) & 1u)) >> 16;
  return (unsigned short)r;
}

__device__ __forceinline__ void gload16(const void* g, void* l) {
  // async global->LDS, 16B per lane; LDS dest = wave-uniform base + lane*16
  __builtin_amdgcn_global_load_lds((const __attribute__((address_space(1))) void*)g,
                                   (__attribute__((address_space(3))) void*)l,
                                   16, 0, 0);
}

// butterfly sum across 16 consecutive lanes (one DPP row) — pure VALU, no DS.
// levels: xor1 (quad_perm 0xB1), xor2 (quad_perm 0x4E),
//         8-group mirror (row_half_mirror 0x141), xor8 (row_ror:8 0x128).
__device__ __forceinline__ float qred16(float x) {
  x += __int_as_float(__builtin_amdgcn_mov_dpp(__float_as_int(x), 0xB1,  0xF, 0xF, true));
  x += __int_as_float(__builtin_amdgcn_mov_dpp(__float_as_int(x), 0x4E,  0xF, 0xF, true));
  x += __int_as_float(__builtin_amdgcn_mov_dpp(__float_as_int(x), 0x141, 0xF, 0xF, true));
  x += __int_as_float(__builtin_amdgcn_mov_dpp(__float_as_int(x), 0x128, 0xF, 0xF, true));
  return x;
}

// ---------------------------------------------------------------- converts
__global__ void cvt_f32_bf16(const float* __restrict__ in, unsigned short* __restrict__ out, int n4) {
  int i = blockIdx.x * blockDim.x + threadIdx.x;
  int stride = gridDim.x * blockDim.x;
  for (; i < n4; i += stride) {
    float4 v = reinterpret_cast<const float4*>(in)[i];
    ushort4 o;
    o.x = f2bf(v.x); o.y = f2bf(v.y); o.z = f2bf(v.z); o.w = f2bf(v.w);
    reinterpret_cast<ushort4*>(out)[i] = o;
  }
}

// ---------------------------------------------------------------- projection GEMM
#define PM 128
#define PN 64
#define PK 64

__global__ void __launch_bounds__(256) proj_gemm(
    const unsigned short* __restrict__ hb, const unsigned short* __restrict__ Wc,
    const float* __restrict__ b_beta, const float* __restrict__ b_alpha,
    float* __restrict__ KQi, float* __restrict__ AVBf, float* __restrict__ gate)
{
  __shared__ unsigned short Asm[PM*PK];  // 16 KB
  __shared__ unsigned short Bsm[PN*PK];  // 8 KB
  const int t = threadIdx.x;
  const int w = t >> 6, lane = t & 63;
  const int bm0 = blockIdx.x * PM;
  const int bn0 = blockIdx.y * PN;

  f32x4 acc[2][4];
  #pragma unroll
  for (int i = 0; i < 2; ++i)
    #pragma unroll
    for (int j = 0; j < 4; ++j) acc[i][j] = (f32x4){0.f, 0.f, 0.f, 0.f};

  for (int k0 = 0; k0 < HID; k0 += PK) {
    #pragma unroll
    for (int it = 0; it < 4; ++it) {
      int unit = t + it * 256;
      int row = unit >> 3, seg = unit & 7;
      int dseg = seg ^ (row & 7);
      const unsigned short* g = hb + (size_t)(bm0 + row) * HID + k0 + dseg * 8;
      gload16(g, (char*)Asm + (w * 1024 + it * 4096));
    }
    #pragma unroll
    for (int it = 0; it < 2; ++it) {
      int unit = t + it * 256;
      int n = unit >> 3, seg = unit & 7;
      int dseg = seg ^ (n & 7);
      const unsigned short* g = Wc + (size_t)(bn0 + n) * HID + k0 + dseg * 8;
      gload16(g, (char*)Bsm + (w * 1024 + it * 4096));
    }
    __syncthreads();
    #pragma unroll
    for (int ks = 0; ks < 2; ++ks) {
      short8 af[2], bfr[4];
      int u = ks * 4 + (lane >> 4);
      int slot = u ^ (lane & 7);
      #pragma unroll
      for (int rb = 0; rb < 2; ++rb) {
        int row = w * 32 + rb * 16 + (lane & 15);
        af[rb] = *(const short8*)((const char*)Asm + row * 128 + slot * 16);
      }
      #pragma unroll
      for (int cb = 0; cb < 4; ++cb) {
        int nn = cb * 16 + (lane & 15);
        bfr[cb] = *(const short8*)((const char*)Bsm + nn * 128 + slot * 16);
      }
      #pragma unroll
      for (int rb = 0; rb < 2; ++rb)
        #pragma unroll
        for (int cb = 0; cb < 4; ++cb)
          acc[rb][cb] = __builtin_amdgcn_mfma_f32_16x16x32_bf16(af[rb], bfr[cb], acc[rb][cb], 0, 0, 0);
    }
    __syncthreads();
  }

  const int p = bn0 >> 8;   // 0:k 1:v 2:q 3:beta 4:alpha 5:gate
  #pragma unroll
  for (int rb = 0; rb < 2; ++rb) {
    #pragma unroll
    for (int cb = 0; cb < 4; ++cb) {
      int n = bn0 + cb * 16 + (lane & 15);
      int rem = n & 255;
      #pragma unroll
      for (int r = 0; r < 4; ++r) {
        int m = bm0 + w * 32 + rb * 16 + (lane >> 4) * 4 + r;
        float v = acc[rb][cb][r];
        int b = m >> 12, tt = m & 4095;
        int h = rem >> 5, d = rem & 31;
        size_t tok = ((size_t)(b * NH + h) * T_ + tt);
        if (p == 0) {
          // interleaved KQ: [tok][g=d>>1][k0 k1 q0 q1]
          KQi[tok * 64 + (d >> 1) * 4 + (d & 1)] = v;
        } else if (p == 2) {
          KQi[tok * 64 + (d >> 1) * 4 + 2 + (d & 1)] = v;
        } else if (p == 5) {
          gate[(size_t)m * SD + rem] = v;
        } else {
          float wv = v;
          if (p == 3) wv = 1.0f / (1.0f + expf(-(v + b_beta[rem])));
          if (p == 4) wv = 1.0f / (1.0f + expf(-(v + b_alpha[rem])));
          int comp = (p == 4) ? 0 : (p == 1) ? 1 : 2;   // (a, v, beta, pad)
          AVBf[(tok * HD + d) * 4 + comp] = wv;
        }
      }
    }
  }
}

// ---------------------------------------------------------------- k normalization (interleaved KQ)
// row = (bh,t): 16 groups x [k0 k1 q0 q1]; element j of k at (j>>1)*4 + (j&1).
__global__ void __launch_bounds__(256) knorm(float* __restrict__ KQi) {
  int t = threadIdx.x;
  size_t row = (size_t)blockIdx.x * 8 + (t >> 5);
  int j = t & 31;
  int off = ((j >> 1) << 2) + (j & 1);
  float x = KQi[row * 64 + off];
  float s = x * x;
  #pragma unroll
  for (int m = 16; m >= 1; m >>= 1) s += __shfl_xor(s, m, 32);
  float inv = 1.0f / fmaxf(sqrtf(s), 1e-12f);
  KQi[row * 64 + off] = x * inv;
}

// ---------------------------------------------------------------- sequential scan
// 512 blocks x 64 threads: block = (rg, bh), bh = blk&63, rg = blk>>6 (4 rows).
// blockIdx%8 == bh%8 -> all 8 row-groups of a bh land on the SAME XCD (L2 dedup
// of the 8x-redundant KQ reads). Lane l: local row il = l>>4, part p = l&15
// (2 state cols as one packed f2). 16-lane dot-reduce = 4 DPP ops (qred16).
// Per step: 1 ds_read_b128 KQ (k2+q2 interleaved) + 1 ds_read_b128 AVB.
// Depth-4 register pipeline (sets A..D, 2 reads each, 8 outstanding):
// exact lgkmcnt(6) waits that formally WRITE the set regs (rule-#18-safe).
// Chunk (32 steps) staged via global_load_lds one chunk ahead; vmcnt(12) =
// 2 ctx-stores (prev chunk) + 10 stage loads (next chunk).
// LDS: KQ[2][8KB] @0, V(avb)[2][2KB] @16384. Total 20KB.
#define CH 32
#define NCH (T_/CH)

#define DSR(dst, areg, imm) \
  asm volatile("ds_read_b128 %0, %1 offset:%c2" : "=v"(dst) : "v"(areg), "i"(imm))

#define SHUF2(V,A,B) __builtin_shufflevector(V, V, A, B)

__global__ void __launch_bounds__(64, 1) scan_kernel(
    const float* __restrict__ KQi, const float4* __restrict__ AVB,
    const float* __restrict__ state_in,
    float* __restrict__ ctx, float* __restrict__ Sfin)
{
  __shared__ __align__(16) char Lds[20480];
  const int blk = blockIdx.x;
  const int bh = blk & 63, rg = blk >> 6;
  const int b = bh >> 3, h = bh & 7;
  const int l = threadIdx.x;
  const int il = l >> 4;     // local row 0..3  (global row = rg*4 + il)
  const int p  = l & 15;     // column part (2 cols: 2p, 2p+1)

  const float*  KQg = KQi + (size_t)bh * (T_ * 64);
  const float4* Vg  = AVB + (size_t)bh * (T_ * HD) + rg * 4;

  f2 S2;
  {
    const float* sp = state_in + (size_t)bh * 1024 + (rg * 4 + il) * 32 + p * 2;
    S2 = (f2){sp[0], sp[1]};
  }

  float* ctxq = ctx + ((size_t)b * T_ + p) * SD + h * HD + rg * 4 + il;
  float osel = 0.0f;

  const uint32_t lds0 = (uint32_t)(uintptr_t)(__attribute__((address_space(3))) char*)&Lds[0];
  const uint32_t a_kq = lds0 + p * 16;            // per-lane KQ fragment base
  const uint32_t a_v  = lds0 + 16384 + il * 16;   // per-lane AVB base

  auto stage = [&](int c2, int buf) {
    const float* kqg = KQg + (size_t)c2 * (CH * 64);
    #pragma unroll
    for (int it = 0; it < 8; ++it)
      gload16(kqg + (size_t)(l + it * 64) * 4, Lds + buf * 8192 + it * 1024);
    const float4* vg = Vg + (size_t)c2 * (CH * HD);
    #pragma unroll
    for (int it = 0; it < 2; ++it) {
      int tc = it * 16 + (l >> 2), r = l & 3;
      gload16(vg + (size_t)tc * HD + r, Lds + 16384 + buf * 2048 + it * 1024);
    }
  };

#define DOSTEP(KQ, VV, T) do { \
    f2 k2_ = SHUF2(KQ, 0, 1); \
    f2 q2_ = SHUF2(KQ, 2, 3); \
    f2 as_ = (f2){VV.x, VV.x} * S2; \
    f2 d_  = k2_ * S2; \
    float pd_ = qred16(d_.x + d_.y); \
    float bv_ = VV.y * VV.z, ba_ = VV.x * VV.z; \
    float u_  = fmaf(-ba_, pd_, bv_); \
    S2 = __builtin_elementwise_fma((f2){u_, u_}, k2_, as_); \
    f2 o_ = q2_ * S2; \
    float od_ = qred16(o_.x + o_.y); \
    osel = (p == ((T) & 15)) ? od_ : osel; \
    if (((T) & 15) == 15) { *ctxq = osel; ctxq += 16 * SD; } \
  } while (0)

  // 4 pipeline sets x {kq, vv} = 32 VGPR staging
  f4 kqA, vvA, kqB, vvB, kqC, vvC, kqD, vvD;

#define R1(S, BUF, T) do { \
    DSR(kq##S, a_kq, (BUF)*8192 + (T)*256); \
    DSR(vv##S, a_v,  (BUF)*2048 + (T)*64); \
  } while (0)

// waitcnt that formally WRITES the set's staged registers: consumers are
// data-dependent on the wait; everything else schedules freely (rule #18).
#define WKA(N, S) \
    asm volatile("s_waitcnt lgkmcnt(" #N ")" : "+v"(kq##S), "+v"(vv##S))

#define C1(S, T) DOSTEP(kq##S, vv##S, T)

#define CHUNKBODY(BUF) do { \
    if (ci == 0)            { asm volatile("s_waitcnt vmcnt(0)"  ::: "memory"); } \
    else if (ci == NCH - 1) { asm volatile("s_waitcnt vmcnt(2)"  ::: "memory"); } \
    else                    { asm volatile("s_waitcnt vmcnt(12)" ::: "memory"); } \
    __builtin_amdgcn_sched_barrier(0); \
    R1(A,BUF,0); R1(B,BUF,1); R1(C,BUF,2); R1(D,BUF,3); \
    WKA(6,A); C1(A, 0); R1(A,BUF, 4); \
    WKA(6,B); C1(B, 1); R1(B,BUF, 5); \
    WKA(6,C); C1(C, 2); R1(C,BUF, 6); \
    WKA(6,D); C1(D, 3); R1(D,BUF, 7); \
    WKA(6,A); C1(A, 4); R1(A,BUF, 8); \
    WKA(6,B); C1(B, 5); R1(B,BUF, 9); \
    WKA(6,C); C1(C, 6); R1(C,BUF,10); \
    WKA(6,D); C1(D, 7); R1(D,BUF,11); \
    WKA(6,A); C1(A, 8); R1(A,BUF,12); \
    WKA(6,B); C1(B, 9); R1(B,BUF,13); \
    WKA(6,C); C1(C,10); R1(C,BUF,14); \
    WKA(6,D); C1(D,11); R1(D,BUF,15); \
    WKA(6,A); C1(A,12); R1(A,BUF,16); \
    WKA(6,B); C1(B,13); R1(B,BUF,17); \
    WKA(6,C); C1(C,14); R1(C,BUF,18); \
    WKA(6,D); C1(D,15); R1(D,BUF,19); \
    WKA(6,A); C1(A,16); R1(A,BUF,20); \
    WKA(6,B); C1(B,17); R1(B,BUF,21); \
    WKA(6,C); C1(C,18); R1(C,BUF,22); \
    WKA(6,D); C1(D,19); R1(D,BUF,23); \
    WKA(6,A); C1(A,20); R1(A,BUF,24); \
    WKA(6,B); C1(B,21); R1(B,BUF,25); \
    WKA(6,C); C1(C,22); R1(C,BUF,26); \
    WKA(6,D); C1(D,23); R1(D,BUF,27); \
    WKA(6,A); C1(A,24); R1(A,BUF,28); \
    WKA(6,B); C1(B,25); R1(B,BUF,29); \
    WKA(6,C); C1(C,26); R1(C,BUF,30); \
    WKA(6,D); C1(D,27); R1(D,BUF,31); \
    WKA(6,A); C1(A,28); \
    WKA(4,B); C1(B,29); \
    WKA(2,C); C1(C,30); \
    WKA(0,D); C1(D,31); \
    if (ci + 2 < NCH) stage(ci + 2, BUF); \
  } while (0)

  stage(0, 0);
  stage(1, 1);
  int ci;
  #pragma unroll 1
  for (int cp = 0; cp < NCH / 2; ++cp) {
    ci = cp * 2;
    CHUNKBODY(0);
    ci = cp * 2 + 1;
    CHUNKBODY(1);
  }

  {
    float* sp = Sfin + (size_t)bh * 1024 + (rg * 4 + il) * 32 + p * 2;
    sp[0] = S2.x; sp[1] = S2.y;
  }
#undef DOSTEP
#undef R1
#undef WKA
#undef C1
#undef CHUNKBODY
}

// ---------------------------------------------------------------- rmsnorm * silu(gate) -> bf16
__global__ void __launch_bounds__(256) rms_silu(
    const float* __restrict__ ctx, const float* __restrict__ gate,
    const float* __restrict__ norm_w, unsigned short* __restrict__ ctx2)
{
  size_t row = (size_t)blockIdx.x * 4 + (threadIdx.x >> 6);
  int lane = threadIdx.x & 63;
  const float4 x = *(const float4*)&ctx[row * SD + lane * 4];
  float s = x.x * x.x + x.y * x.y + x.z * x.z + x.w * x.w;
  #pragma unroll
  for (int m = 32; m >= 1; m >>= 1) s += __shfl_xor(s, m, 64);
  float rs = 1.0f / sqrtf(s * (1.0f / 256.0f) + 1e-6f);
  const float4 g = *(const float4*)&gate[row * SD + lane * 4];
  const float4 w = *(const float4*)&norm_w[lane * 4];
  ushort4 o;
  o.x = f2bf(x.x * rs * w.x * (g.x / (1.0f + expf(-g.x))));
  o.y = f2bf(x.y * rs * w.y * (g.y / (1.0f + expf(-g.y))));
  o.z = f2bf(x.z * rs * w.z * (g.z / (1.0f + expf(-g.z))));
  o.w = f2bf(x.w * rs * w.w * (g.w / (1.0f + expf(-g.w))));
  *(ushort4*)&ctx2[row * SD + lane * 4] = o;
}

// ---------------------------------------------------------------- output GEMM
__global__ void __launch_bounds__(256) out_gemm(
    const unsigned short* __restrict__ ctx2, const unsigned short* __restrict__ Wob,
    float* __restrict__ out)
{
  __shared__ unsigned short Asm[PM*PK];
  __shared__ unsigned short Bsm[PN*PK];
  const int t = threadIdx.x;
  const int w = t >> 6, lane = t & 63;
  const int bm0 = blockIdx.x * PM;
  const int bn0 = blockIdx.y * PN;

  f32x4 acc[2][4];
  #pragma unroll
  for (int i = 0; i < 2; ++i)
    #pragma unroll
    for (int j = 0; j < 4; ++j) acc[i][j] = (f32x4){0.f, 0.f, 0.f, 0.f};

  for (int k0 = 0; k0 < SD; k0 += PK) {
    #pragma unroll
    for (int it = 0; it < 4; ++it) {
      int unit = t + it * 256;
      int row = unit >> 3, seg = unit & 7;
      int dseg = seg ^ (row & 7);
      const unsigned short* g = ctx2 + (size_t)(bm0 + row) * SD + k0 + dseg * 8;
      gload16(g, (char*)Asm + (w * 1024 + it * 4096));
    }
    #pragma unroll
    for (int it = 0; it < 2; ++it) {
      int unit = t + it * 256;
      int n = unit >> 3, seg = unit & 7;
      int dseg = seg ^ (n & 7);
      const unsigned short* g = Wob + (size_t)(bn0 + n) * SD + k0 + dseg * 8;
      gload16(g, (char*)Bsm + (w * 1024 + it * 4096));
    }
    __syncthreads();
    #pragma unroll
    for (int ks = 0; ks < 2; ++ks) {
      short8 af[2], bfr[4];
      int u = ks * 4 + (lane >> 4);
      int slot = u ^ (lane & 7);
      #pragma unroll
      for (int rb = 0; rb < 2; ++rb) {
        int row = w * 32 + rb * 16 + (lane & 15);
        af[rb] = *(const short8*)((const char*)Asm + row * 128 + slot * 16);
      }
      #pragma unroll
      for (int cb = 0; cb < 4; ++cb) {
        int nn = cb * 16 + (lane & 15);
        bfr[cb] = *(const short8*)((const char*)Bsm + nn * 128 + slot * 16);
      }
      #pragma unroll
      for (int rb = 0; rb < 2; ++rb)
        #pragma unroll
        for (int cb = 0; cb < 4; ++cb)
          acc[rb][cb] = __builtin_amdgcn_mfma_f32_16x16x32_bf16(af[rb], bfr[cb], acc[rb][cb], 0, 0, 0);
    }
    __syncthreads();
  }
  #pragma unroll
  for (int rb = 0; rb < 2; ++rb)
    #pragma unroll
    for (int cb = 0; cb < 4; ++cb) {
      int n = bn0 + cb * 16 + (lane & 15);
      #pragma unroll
      for (int r = 0; r < 4; ++r) {
        int m = bm0 + w * 32 + rb * 16 + (lane >> 4) * 4 + r;
        out[(size_t)m * 512 + n] = acc[rb][cb][r];
      }
    }
}

// ---------------------------------------------------------------- launcher
// ws layout (bytes), total 253,493,248:
//   hb   bf16 [32768][512]            @ 0
//   Wc   bf16 [1536][512]             @ 33,554,432
//   Wob  bf16 [512][256]              @ 35,127,296
//   KQi  f32  [64][4096][64]          @ 35,389,440   (16 groups x [k0 k1 q0 q1])
//   AVB  f32x4 [64][4096][32]         @ 102,498,304  (a, v, beta, pad)
//   ctx2 bf16 [32768][256]            @ 236,716,032
// d_out reuse: ctx f32 [32768][256] @ 0; gate f32 [32768][256] @ +8388608 floats
// (both overwritten later by out_gemm); Sfin @ +16777216 floats.
extern "C" void kernel_launch(void* const* d_in, const int* in_sizes, int n_in,
                              void* d_out, int out_size, void* d_ws, size_t ws_size,
                              hipStream_t stream) {
  (void)in_sizes; (void)n_in; (void)out_size; (void)ws_size;
  const float* hidden  = (const float*)d_in[0];
  const float* state   = (const float*)d_in[1];
  const float* W_k     = (const float*)d_in[2];
  const float* W_v     = (const float*)d_in[3];
  const float* W_q     = (const float*)d_in[4];
  const float* W_beta  = (const float*)d_in[5];
  const float* b_beta  = (const float*)d_in[6];
  const float* W_alpha = (const float*)d_in[7];
  const float* b_alpha = (const float*)d_in[8];
  const float* W_out   = (const float*)d_in[9];
  const float* gate_W  = (const float*)d_in[10];
  const float* norm_w  = (const float*)d_in[11];
  float* out = (float*)d_out;

  char* ws = (char*)d_ws;
  unsigned short* hb  = (unsigned short*)(ws);
  unsigned short* Wc  = (unsigned short*)(ws + 33554432);
  unsigned short* Wob = (unsigned short*)(ws + 35127296);
  float* KQi  = (float*)(ws + 35389440);
  float* AVBf = (float*)(ws + 102498304);
  unsigned short* ctx2 = (unsigned short*)(ws + 236716032);
  float* ctx  = out;                 // fp32 scratch, overwritten by out_gemm
  float* gate = out + 8388608;       // fp32 scratch, overwritten by out_gemm
  float* Sfin = out + 16777216;      // final state output

  cvt_f32_bf16<<<2048, 256, 0, stream>>>(hidden, hb, M_TOK * HID / 4);
  cvt_f32_bf16<<<64, 256, 0, stream>>>(W_k,     Wc + 0 * 131072, 32768);
  cvt_f32_bf16<<<64, 256, 0, stream>>>(W_v,     Wc + 1 * 131072, 32768);
  cvt_f32_bf16<<<64, 256, 0, stream>>>(W_q,     Wc + 2 * 131072, 32768);
  cvt_f32_bf16<<<64, 256, 0, stream>>>(W_beta,  Wc + 3 * 131072, 32768);
  cvt_f32_bf16<<<64, 256, 0, stream>>>(W_alpha, Wc + 4 * 131072, 32768);
  cvt_f32_bf16<<<64, 256, 0, stream>>>(gate_W,  Wc + 5 * 131072, 32768);
  cvt_f32_bf16<<<64, 256, 0, stream>>>(W_out,   Wob, 32768);

  proj_gemm<<<dim3(256, 24), 256, 0, stream>>>(hb, Wc, b_beta, b_alpha, KQi, AVBf, gate);
  knorm<<<32768, 256, 0, stream>>>(KQi);
  scan_kernel<<<512, 64, 0, stream>>>(KQi, (const float4*)AVBf, state, ctx, Sfin);
  rms_silu<<<8192, 256, 0, stream>>>(ctx, gate, norm_w, ctx2);
  out_gemm<<<dim3(256, 8), 256, 0, stream>>>(ctx2, Wob, out);
}

// Round 8
// 536.669 us; speedup vs baseline: 1.1859x; 1.1273x over previous
//
#include <hip/hip_runtime.h>
#include <stdint.h>

// Problem constants
#define B_    8
#define T_    4096
#define HID   512
#define SD    256
#define NH    8
#define HD    32
#define M_TOK (B_*T_)          // 32768 tokens
#define NPROJ 1536             // 6 * 256 output channels (k,v,q,beta,alpha,gate)

typedef __attribute__((ext_vector_type(8))) short short8;   // 8 bf16 (4 VGPRs) — MFMA A/B frag
typedef __attribute__((ext_vector_type(4))) float f32x4;    // MFMA C/D frag
typedef __attribute__((ext_vector_type(4))) float f4;       // asm ds_read_b128 dst
typedef __attribute__((ext_vector_type(2))) float f2;       // packed fp32 (v_pk_*_f32)

__device__ __forceinline__ unsigned short f2bf(float f) {
  uint32_t u = __float_as_uint(f);
  uint32_t r = (u + 0x7fffu + ((u >> 16) & 1u)) >> 16;
  return (unsigned short)r;
}

__device__ __forceinline__ void gload16(const void* g, void* l) {
  // async global->LDS, 16B per lane; LDS dest = wave-uniform base + lane*16
  __builtin_amdgcn_global_load_lds((const __attribute__((address_space(1))) void*)g,
                                   (__attribute__((address_space(3))) void*)l,
                                   16, 0, 0);
}

// butterfly sum across 16 consecutive lanes (one DPP row) — pure VALU, no DS.
// Builtin mov_dpp so the compiler inserts any required DPP hazard wait-states.
__device__ __forceinline__ float qred16(float x) {
  x += __int_as_float(__builtin_amdgcn_mov_dpp(__float_as_int(x), 0xB1,  0xF, 0xF, true));
  x += __int_as_float(__builtin_amdgcn_mov_dpp(__float_as_int(x), 0x4E,  0xF, 0xF, true));
  x += __int_as_float(__builtin_amdgcn_mov_dpp(__float_as_int(x), 0x141, 0xF, 0xF, true));
  x += __int_as_float(__builtin_amdgcn_mov_dpp(__float_as_int(x), 0x128, 0xF, 0xF, true));
  return x;
}

// ---------------------------------------------------------------- converts
__global__ void cvt_f32_bf16(const float* __restrict__ in, unsigned short* __restrict__ out, int n4) {
  int i = blockIdx.x * blockDim.x + threadIdx.x;
  int stride = gridDim.x * blockDim.x;
  for (; i < n4; i += stride) {
    float4 v = reinterpret_cast<const float4*>(in)[i];
    ushort4 o;
    o.x = f2bf(v.x); o.y = f2bf(v.y); o.z = f2bf(v.z); o.w = f2bf(v.w);
    reinterpret_cast<ushort4*>(out)[i] = o;
  }
}

// ---------------------------------------------------------------- projection GEMM
#define PM 128
#define PN 64
#define PK 64

__global__ void __launch_bounds__(256) proj_gemm(
    const unsigned short* __restrict__ hb, const unsigned short* __restrict__ Wc,
    const float* __restrict__ b_beta, const float* __restrict__ b_alpha,
    float* __restrict__ KQi, float* __restrict__ AVBf, float* __restrict__ gate)
{
  __shared__ unsigned short Asm[PM*PK];  // 16 KB
  __shared__ unsigned short Bsm[PN*PK];  // 8 KB
  const int t = threadIdx.x;
  const int w = t >> 6, lane = t & 63;
  const int bm0 = blockIdx.x * PM;
  const int bn0 = blockIdx.y * PN;

  f32x4 acc[2][4];
  #pragma unroll
  for (int i = 0; i < 2; ++i)
    #pragma unroll
    for (int j = 0; j < 4; ++j) acc[i][j] = (f32x4){0.f, 0.f, 0.f, 0.f};

  for (int k0 = 0; k0 < HID; k0 += PK) {
    #pragma unroll
    for (int it = 0; it < 4; ++it) {
      int unit = t + it * 256;
      int row = unit >> 3, seg = unit & 7;
      int dseg = seg ^ (row & 7);
      const unsigned short* g = hb + (size_t)(bm0 + row) * HID + k0 + dseg * 8;
      gload16(g, (char*)Asm + (w * 1024 + it * 4096));
    }
    #pragma unroll
    for (int it = 0; it < 2; ++it) {
      int unit = t + it * 256;
      int n = unit >> 3, seg = unit & 7;
      int dseg = seg ^ (n & 7);
      const unsigned short* g = Wc + (size_t)(bn0 + n) * HID + k0 + dseg * 8;
      gload16(g, (char*)Bsm + (w * 1024 + it * 4096));
    }
    __syncthreads();
    #pragma unroll
    for (int ks = 0; ks < 2; ++ks) {
      short8 af[2], bfr[4];
      int u = ks * 4 + (lane >> 4);
      int slot = u ^ (lane & 7);
      #pragma unroll
      for (int rb = 0; rb < 2; ++rb) {
        int row = w * 32 + rb * 16 + (lane & 15);
        af[rb] = *(const short8*)((const char*)Asm + row * 128 + slot * 16);
      }
      #pragma unroll
      for (int cb = 0; cb < 4; ++cb) {
        int nn = cb * 16 + (lane & 15);
        bfr[cb] = *(const short8*)((const char*)Bsm + nn * 128 + slot * 16);
      }
      #pragma unroll
      for (int rb = 0; rb < 2; ++rb)
        #pragma unroll
        for (int cb = 0; cb < 4; ++cb)
          acc[rb][cb] = __builtin_amdgcn_mfma_f32_16x16x32_bf16(af[rb], bfr[cb], acc[rb][cb], 0, 0, 0);
    }
    __syncthreads();
  }

  const int p = bn0 >> 8;   // 0:k 1:v 2:q 3:beta 4:alpha 5:gate
  #pragma unroll
  for (int rb = 0; rb < 2; ++rb) {
    #pragma unroll
    for (int cb = 0; cb < 4; ++cb) {
      int n = bn0 + cb * 16 + (lane & 15);
      int rem = n & 255;
      #pragma unroll
      for (int r = 0; r < 4; ++r) {
        int m = bm0 + w * 32 + rb * 16 + (lane >> 4) * 4 + r;
        float v = acc[rb][cb][r];
        int b = m >> 12, tt = m & 4095;
        int h = rem >> 5, d = rem & 31;
        size_t tok = ((size_t)(b * NH + h) * T_ + tt);
        if (p == 0) {
          // interleaved KQ: [tok][g=d>>1][k0 k1 q0 q1]
          KQi[tok * 64 + (d >> 1) * 4 + (d & 1)] = v;
        } else if (p == 2) {
          KQi[tok * 64 + (d >> 1) * 4 + 2 + (d & 1)] = v;
        } else if (p == 5) {
          gate[(size_t)m * SD + rem] = v;
        } else {
          float wv = v;
          if (p == 3) wv = 1.0f / (1.0f + expf(-(v + b_beta[rem])));
          if (p == 4) wv = 1.0f / (1.0f + expf(-(v + b_alpha[rem])));
          int comp = (p == 4) ? 0 : (p == 1) ? 1 : 2;   // (a, v, beta, pad)
          AVBf[(tok * HD + d) * 4 + comp] = wv;
        }
      }
    }
  }
}

// ---------------------------------------------------------------- k normalization (interleaved KQ)
__global__ void __launch_bounds__(256) knorm(float* __restrict__ KQi) {
  int t = threadIdx.x;
  size_t row = (size_t)blockIdx.x * 8 + (t >> 5);
  int j = t & 31;
  int off = ((j >> 1) << 2) + (j & 1);
  float x = KQi[row * 64 + off];
  float s = x * x;
  #pragma unroll
  for (int m = 16; m >= 1; m >>= 1) s += __shfl_xor(s, m, 32);
  float inv = 1.0f / fmaxf(sqrtf(s), 1e-12f);
  KQi[row * 64 + off] = x * inv;
}

// ---------------------------------------------------------------- sequential scan
// 512 blocks x 128 threads (2 waves). block = (rg, bh): bh = blk&63, rg = blk>>6.
// WAVE0 (consumer): lane l: local row il = l>>4 (global row rg*4+il), part p = l&15
// (2 state cols packed f2). Per step: 1 ds_read_b128 KQ + 1 ds_read_b128 AVB +
// ~16 VALU; in-chain 16-lane reduce = qred16 (builtin DPP). Readout partial
// (1 pk mul + 1 add) fire-and-forgotten to an LDS ring (ds_write_b32, 4 bufs
// of 16 steps: offset PB*4096 + (T&15)*256). Depth-4 register pipeline with
// exact per-step lgkmcnt waits (6,7,8,9..9,7,5,3) that formally WRITE the
// consumed set's regs (rule-#18-safe). NO vmem waits on wave0.
// WAVE1 (producer): stages chunk ci+1 via global_load_lds during chunk ci
// (vmcnt(0) before the chunk-boundary barrier); per group g reduces partial
// buffer g-2 (4 ds_read_b128 + f4 tree + 1 coalesced ctx store). Retirement
// guarantee: wave0's lgkm bound (<=10 outstanding) + 48 intervening lgkm ops
// => g-2's writes retired >= 1 barrier before the read. 4 s_barrier / 64 steps.
// LDS: KQ dbuf 16KB @0, AVB dbuf 4KB @16384, partial ring 4x4KB @20480 = 36KB.
#define CH 32
#define NCH (T_/CH)

#define DSR(dst, areg, imm) \
  asm volatile("ds_read_b128 %0, %1 offset:%c2" : "=v"(dst) : "v"(areg), "i"(imm))

#define SHUF2(V,A,B) __builtin_shufflevector(V, V, A, B)

#define BAR asm volatile("s_barrier" ::: "memory")

__global__ void __launch_bounds__(128, 1) scan_kernel(
    const float* __restrict__ KQi, const float4* __restrict__ AVB,
    const float* __restrict__ state_in,
    float* __restrict__ ctx, float* __restrict__ Sfin)
{
  __shared__ __align__(16) char Lds[36864];
  const int blk = blockIdx.x;
  const int bh = blk & 63, rg = blk >> 6;
  const int b = bh >> 3, h = bh & 7;
  const int tid = threadIdx.x;
  const int wid = tid >> 6;
  const int lw = tid & 63;

  const float*  KQg = KQi + (size_t)bh * (T_ * 64);
  const float4* Vg  = AVB + (size_t)bh * (T_ * HD) + rg * 4;

  const uint32_t lds0 = (uint32_t)(uintptr_t)(__attribute__((address_space(3))) char*)&Lds[0];

  if (wid == 1) {
    // ---------------- WAVE1: producer (staging) + readout reducer ----------------
    const int il1 = lw >> 4, tq = lw & 15;
    const uint32_t a_pr = lds0 + 20480 + tq * 256 + il1 * 64;
    float* ctxb = ctx + (size_t)b * T_ * SD + h * HD + rg * 4 + il1;

    auto stageW = [&](int c2, int buf) {
      const float* kqg = KQg + (size_t)c2 * (CH * 64);
      #pragma unroll
      for (int it = 0; it < 8; ++it)
        gload16(kqg + (size_t)(lw + it * 64) * 4, Lds + buf * 8192 + it * 1024);
      const float4* vg = Vg + (size_t)c2 * (CH * HD);
      #pragma unroll
      for (int it = 0; it < 2; ++it) {
        int tc = it * 16 + (lw >> 2), r = lw & 3;
        gload16(vg + (size_t)tc * HD + r, Lds + 16384 + buf * 2048 + it * 1024);
      }
    };

#define REDUCE(PB, T0) do { \
      f4 r0_, r1_, r2_, r3_; \
      DSR(r0_, a_pr, (PB)*4096 + 0);  DSR(r1_, a_pr, (PB)*4096 + 16); \
      DSR(r2_, a_pr, (PB)*4096 + 32); DSR(r3_, a_pr, (PB)*4096 + 48); \
      asm volatile("s_waitcnt lgkmcnt(0)" : "+v"(r0_), "+v"(r1_), "+v"(r2_), "+v"(r3_)); \
      f4 s_ = (r0_ + r1_) + (r2_ + r3_); \
      float v_ = (s_.x + s_.y) + (s_.z + s_.w); \
      ctxb[(size_t)((T0) + tq) * SD] = v_; \
    } while (0)

    stageW(0, 0);
    asm volatile("s_waitcnt vmcnt(0)" ::: "memory");
    BAR;   // prologue: chunk 0 staged
    #pragma unroll 1
    for (int cp = 0; cp < NCH / 2; ++cp) {
      // chunk 2cp, group 4cp
      if (cp > 0) REDUCE(2, 64 * cp - 32);
      stageW(2 * cp + 1, 1);
      BAR;
      // group 4cp+1
      if (cp > 0) REDUCE(3, 64 * cp - 16);
      asm volatile("s_waitcnt vmcnt(0)" ::: "memory");
      BAR;
      // chunk 2cp+1, group 4cp+2
      REDUCE(0, 64 * cp);
      if (cp < NCH / 2 - 1) stageW(2 * cp + 2, 0);
      BAR;
      // group 4cp+3
      REDUCE(1, 64 * cp + 16);
      asm volatile("s_waitcnt vmcnt(0)" ::: "memory");
      BAR;
    }
    BAR;  // final sync (wave0 drained its last partial writes)
    REDUCE(2, T_ - 32);
    REDUCE(3, T_ - 16);
#undef REDUCE
    return;
  }

  // ---------------- WAVE0: the sequential recurrence ----------------
  const int il = lw >> 4;    // local row
  const int p  = lw & 15;    // column part (cols 2p, 2p+1)

  f2 S2;
  {
    const float* sp = state_in + (size_t)bh * 1024 + (rg * 4 + il) * 32 + p * 2;
    S2 = (f2){sp[0], sp[1]};
  }

  const uint32_t a_kq = lds0 + p * 16;
  const uint32_t a_v  = lds0 + 16384 + il * 16;
  const uint32_t a_pw = lds0 + 20480 + lw * 4;

#define C1(S, T, PB) do { \
    f2 k2_ = SHUF2(kq##S, 0, 1); \
    f2 q2_ = SHUF2(kq##S, 2, 3); \
    f4 VV_ = vv##S; \
    f2 as_ = (f2){VV_.x, VV_.x} * S2; \
    f2 d_  = k2_ * S2; \
    float pd_ = qred16(d_.x + d_.y); \
    float bv_ = VV_.y * VV_.z, ba_ = VV_.x * VV_.z; \
    float u_ = fmaf(-ba_, pd_, bv_); \
    S2 = __builtin_elementwise_fma((f2){u_, u_}, k2_, as_); \
    f2 o_ = q2_ * S2; \
    float po_ = o_.x + o_.y; \
    asm volatile("ds_write_b32 %0, %1 offset:%c2" :: "v"(a_pw), "v"(po_), "i"((PB)*4096 + ((T)&15)*256)); \
  } while (0)

  f4 kqA, vvA, kqB, vvB, kqC, vvC, kqD, vvD;

#define R1(S, BUF, T) do { \
    DSR(kq##S, a_kq, (BUF)*8192 + (T)*256); \
    DSR(vv##S, a_v,  (BUF)*2048 + (T)*64); \
  } while (0)

#define WKA(N, S) \
    asm volatile("s_waitcnt lgkmcnt(" #N ")" : "+v"(kq##S), "+v"(vv##S))

#define CHUNK(BUF, PBa, PBb) do { \
    R1(A,BUF,0); R1(B,BUF,1); R1(C,BUF,2); R1(D,BUF,3); \
    WKA(6,A); C1(A, 0,PBa); R1(A,BUF, 4); \
    WKA(7,B); C1(B, 1,PBa); R1(B,BUF, 5); \
    WKA(8,C); C1(C, 2,PBa); R1(C,BUF, 6); \
    WKA(9,D); C1(D, 3,PBa); R1(D,BUF, 7); \
    WKA(9,A); C1(A, 4,PBa); R1(A,BUF, 8); \
    WKA(9,B); C1(B, 5,PBa); R1(B,BUF, 9); \
    WKA(9,C); C1(C, 6,PBa); R1(C,BUF,10); \
    WKA(9,D); C1(D, 7,PBa); R1(D,BUF,11); \
    WKA(9,A); C1(A, 8,PBa); R1(A,BUF,12); \
    WKA(9,B); C1(B, 9,PBa); R1(B,BUF,13); \
    WKA(9,C); C1(C,10,PBa); R1(C,BUF,14); \
    WKA(9,D); C1(D,11,PBa); R1(D,BUF,15); \
    WKA(9,A); C1(A,12,PBa); R1(A,BUF,16); \
    WKA(9,B); C1(B,13,PBa); R1(B,BUF,17); \
    WKA(9,C); C1(C,14,PBa); R1(C,BUF,18); \
    WKA(9,D); C1(D,15,PBa); R1(D,BUF,19); \
    BAR; \
    WKA(9,A); C1(A,16,PBb); R1(A,BUF,20); \
    WKA(9,B); C1(B,17,PBb); R1(B,BUF,21); \
    WKA(9,C); C1(C,18,PBb); R1(C,BUF,22); \
    WKA(9,D); C1(D,19,PBb); R1(D,BUF,23); \
    WKA(9,A); C1(A,20,PBb); R1(A,BUF,24); \
    WKA(9,B); C1(B,21,PBb); R1(B,BUF,25); \
    WKA(9,C); C1(C,22,PBb); R1(C,BUF,26); \
    WKA(9,D); C1(D,23,PBb); R1(D,BUF,27); \
    WKA(9,A); C1(A,24,PBb); R1(A,BUF,28); \
    WKA(9,B); C1(B,25,PBb); R1(B,BUF,29); \
    WKA(9,C); C1(C,26,PBb); R1(C,BUF,30); \
    WKA(9,D); C1(D,27,PBb); R1(D,BUF,31); \
    WKA(9,A); C1(A,28,PBb); \
    WKA(7,B); C1(B,29,PBb); \
    WKA(5,C); C1(C,30,PBb); \
    WKA(3,D); C1(D,31,PBb); \
    BAR; \
  } while (0)

  BAR;   // prologue: wait for wave1's stage(0)
  #pragma unroll 1
  for (int cp = 0; cp < NCH / 2; ++cp) {
    CHUNK(0, 0, 1);
    CHUNK(1, 2, 3);
  }
  asm volatile("s_waitcnt lgkmcnt(0)" ::: "memory");
  BAR;   // final: partial writes of last group now visible/retired

  {
    float* sp = Sfin + (size_t)bh * 1024 + (rg * 4 + il) * 32 + p * 2;
    sp[0] = S2.x; sp[1] = S2.y;
  }
#undef C1
#undef R1
#undef WKA
#undef CHUNK
}

// ---------------------------------------------------------------- rmsnorm * silu(gate) -> bf16
__global__ void __launch_bounds__(256) rms_silu(
    const float* __restrict__ ctx, const float* __restrict__ gate,
    const float* __restrict__ norm_w, unsigned short* __restrict__ ctx2)
{
  size_t row = (size_t)blockIdx.x * 4 + (threadIdx.x >> 6);
  int lane = threadIdx.x & 63;
  const float4 x = *(const float4*)&ctx[row * SD + lane * 4];
  float s = x.x * x.x + x.y * x.y + x.z * x.z + x.w * x.w;
  #pragma unroll
  for (int m = 32; m >= 1; m >>= 1) s += __shfl_xor(s, m, 64);
  float rs = 1.0f / sqrtf(s * (1.0f / 256.0f) + 1e-6f);
  const float4 g = *(const float4*)&gate[row * SD + lane * 4];
  const float4 w = *(const float4*)&norm_w[lane * 4];
  ushort4 o;
  o.x = f2bf(x.x * rs * w.x * (g.x / (1.0f + expf(-g.x))));
  o.y = f2bf(x.y * rs * w.y * (g.y / (1.0f + expf(-g.y))));
  o.z = f2bf(x.z * rs * w.z * (g.z / (1.0f + expf(-g.z))));
  o.w = f2bf(x.w * rs * w.w * (g.w / (1.0f + expf(-g.w))));
  *(ushort4*)&ctx2[row * SD + lane * 4] = o;
}

// ---------------------------------------------------------------- output GEMM
__global__ void __launch_bounds__(256) out_gemm(
    const unsigned short* __restrict__ ctx2, const unsigned short* __restrict__ Wob,
    float* __restrict__ out)
{
  __shared__ unsigned short Asm[PM*PK];
  __shared__ unsigned short Bsm[PN*PK];
  const int t = threadIdx.x;
  const int w = t >> 6, lane = t & 63;
  const int bm0 = blockIdx.x * PM;
  const int bn0 = blockIdx.y * PN;

  f32x4 acc[2][4];
  #pragma unroll
  for (int i = 0; i < 2; ++i)
    #pragma unroll
    for (int j = 0; j < 4; ++j) acc[i][j] = (f32x4){0.f, 0.f, 0.f, 0.f};

  for (int k0 = 0; k0 < SD; k0 += PK) {
    #pragma unroll
    for (int it = 0; it < 4; ++it) {
      int unit = t + it * 256;
      int row = unit >> 3, seg = unit & 7;
      int dseg = seg ^ (row & 7);
      const unsigned short* g = ctx2 + (size_t)(bm0 + row) * SD + k0 + dseg * 8;
      gload16(g, (char*)Asm + (w * 1024 + it * 4096));
    }
    #pragma unroll
    for (int it = 0; it < 2; ++it) {
      int unit = t + it * 256;
      int n = unit >> 3, seg = unit & 7;
      int dseg = seg ^ (n & 7);
      const unsigned short* g = Wob + (size_t)(bn0 + n) * SD + k0 + dseg * 8;
      gload16(g, (char*)Bsm + (w * 1024 + it * 4096));
    }
    __syncthreads();
    #pragma unroll
    for (int ks = 0; ks < 2; ++ks) {
      short8 af[2], bfr[4];
      int u = ks * 4 + (lane >> 4);
      int slot = u ^ (lane & 7);
      #pragma unroll
      for (int rb = 0; rb < 2; ++rb) {
        int row = w * 32 + rb * 16 + (lane & 15);
        af[rb] = *(const short8*)((const char*)Asm + row * 128 + slot * 16);
      }
      #pragma unroll
      for (int cb = 0; cb < 4; ++cb) {
        int nn = cb * 16 + (lane & 15);
        bfr[cb] = *(const short8*)((const char*)Bsm + nn * 128 + slot * 16);
      }
      #pragma unroll
      for (int rb = 0; rb < 2; ++rb)
        #pragma unroll
        for (int cb = 0; cb < 4; ++cb)
          acc[rb][cb] = __builtin_amdgcn_mfma_f32_16x16x32_bf16(af[rb], bfr[cb], acc[rb][cb], 0, 0, 0);
    }
    __syncthreads();
  }
  #pragma unroll
  for (int rb = 0; rb < 2; ++rb)
    #pragma unroll
    for (int cb = 0; cb < 4; ++cb) {
      int n = bn0 + cb * 16 + (lane & 15);
      #pragma unroll
      for (int r = 0; r < 4; ++r) {
        int m = bm0 + w * 32 + rb * 16 + (lane >> 4) * 4 + r;
        out[(size_t)m * 512 + n] = acc[rb][cb][r];
      }
    }
}

// ---------------------------------------------------------------- launcher
// ws layout (bytes), total 253,493,248:
//   hb   bf16 [32768][512]            @ 0
//   Wc   bf16 [1536][512]             @ 33,554,432
//   Wob  bf16 [512][256]              @ 35,127,296
//   KQi  f32  [64][4096][64]          @ 35,389,440   (16 groups x [k0 k1 q0 q1])
//   AVB  f32x4 [64][4096][32]         @ 102,498,304  (a, v, beta, pad)
//   ctx2 bf16 [32768][256]            @ 236,716,032
// d_out reuse: ctx f32 [32768][256] @ 0; gate f32 [32768][256] @ +8388608 floats
// (both overwritten later by out_gemm); Sfin @ +16777216 floats.
extern "C" void kernel_launch(void* const* d_in, const int* in_sizes, int n_in,
                              void* d_out, int out_size, void* d_ws, size_t ws_size,
                              hipStream_t stream) {
  (void)in_sizes; (void)n_in; (void)out_size; (void)ws_size;
  const float* hidden  = (const float*)d_in[0];
  const float* state   = (const float*)d_in[1];
  const float* W_k     = (const float*)d_in[2];
  const float* W_v     = (const float*)d_in[3];
  const float* W_q     = (const float*)d_in[4];
  const float* W_beta  = (const float*)d_in[5];
  const float* b_beta  = (const float*)d_in[6];
  const float* W_alpha = (const float*)d_in[7];
  const float* b_alpha = (const float*)d_in[8];
  const float* W_out   = (const float*)d_in[9];
  const float* gate_W  = (const float*)d_in[10];
  const float* norm_w  = (const float*)d_in[11];
  float* out = (float*)d_out;

  char* ws = (char*)d_ws;
  unsigned short* hb  = (unsigned short*)(ws);
  unsigned short* Wc  = (unsigned short*)(ws + 33554432);
  unsigned short* Wob = (unsigned short*)(ws + 35127296);
  float* KQi  = (float*)(ws + 35389440);
  float* AVBf = (float*)(ws + 102498304);
  unsigned short* ctx2 = (unsigned short*)(ws + 236716032);
  float* ctx  = out;                 // fp32 scratch, overwritten by out_gemm
  float* gate = out + 8388608;       // fp32 scratch, overwritten by out_gemm
  float* Sfin = out + 16777216;      // final state output

  cvt_f32_bf16<<<2048, 256, 0, stream>>>(hidden, hb, M_TOK * HID / 4);
  cvt_f32_bf16<<<64, 256, 0, stream>>>(W_k,     Wc + 0 * 131072, 32768);
  cvt_f32_bf16<<<64, 256, 0, stream>>>(W_v,     Wc + 1 * 131072, 32768);
  cvt_f32_bf16<<<64, 256, 0, stream>>>(W_q,     Wc + 2 * 131072, 32768);
  cvt_f32_bf16<<<64, 256, 0, stream>>>(W_beta,  Wc + 3 * 131072, 32768);
  cvt_f32_bf16<<<64, 256, 0, stream>>>(W_alpha, Wc + 4 * 131072, 32768);
  cvt_f32_bf16<<<64, 256, 0, stream>>>(gate_W,  Wc + 5 * 131072, 32768);
  cvt_f32_bf16<<<64, 256, 0, stream>>>(W_out,   Wob, 32768);

  proj_gemm<<<dim3(256, 24), 256, 0, stream>>>(hb, Wc, b_beta, b_alpha, KQi, AVBf, gate);
  knorm<<<32768, 256, 0, stream>>>(KQi);
  scan_kernel<<<512, 128, 0, stream>>>(KQi, (const float4*)AVBf, state, ctx, Sfin);
  rms_silu<<<8192, 256, 0, stream>>>(ctx, gate, norm_w, ctx2);
  out_gemm<<<dim3(256, 8), 256, 0, stream>>>(ctx2, Wob, out);
}

// Round 9
// 507.529 us; speedup vs baseline: 1.2540x; 1.0574x over previous
//
#include <hip/hip_runtime.h>
#include <stdint.h>

// Problem constants
#define B_    8
#define T_    4096
#define HID   512
#define SD    256
#define NH    8
#define HD    32
#define M_TOK (B_*T_)          // 32768 tokens
#define NPROJ 1536             // 6 * 256 output channels (k,v,q,beta,alpha,gate)

typedef __attribute__((ext_vector_type(8))) short short8;   // 8 bf16 (4 VGPRs) — MFMA A/B frag
typedef __attribute__((ext_vector_type(4))) float f32x4;    // MFMA C/D frag
typedef __attribute__((ext_vector_type(4))) float f4;       // asm ds_read_b128 dst
typedef __attribute__((ext_vector_type(2))) float f2;       // packed fp32 (v_pk_*_f32)

__device__ __forceinline__ unsigned short f2bf(float f) {
  uint32_t u = __float_as_uint(f);
  uint32_t r = (u + 0x7fffu + ((u >> 16) & 1u)) >> 16;
  return (unsigned short)r;
}

__device__ __forceinline__ void gload16(const void* g, void* l) {
  // async global->LDS, 16B per lane; LDS dest = wave-uniform base + lane*16
  __builtin_amdgcn_global_load_lds((const __attribute__((address_space(1))) void*)g,
                                   (__attribute__((address_space(3))) void*)l,
                                   16, 0, 0);
}

// butterfly sum across 16 consecutive lanes (one DPP row) — pure VALU, no DS.
__device__ __forceinline__ float qred16(float x) {
  x += __int_as_float(__builtin_amdgcn_mov_dpp(__float_as_int(x), 0xB1,  0xF, 0xF, true));
  x += __int_as_float(__builtin_amdgcn_mov_dpp(__float_as_int(x), 0x4E,  0xF, 0xF, true));
  x += __int_as_float(__builtin_amdgcn_mov_dpp(__float_as_int(x), 0x141, 0xF, 0xF, true));
  x += __int_as_float(__builtin_amdgcn_mov_dpp(__float_as_int(x), 0x128, 0xF, 0xF, true));
  return x;
}

// ---------------------------------------------------------------- converts
__global__ void cvt_f32_bf16(const float* __restrict__ in, unsigned short* __restrict__ out, int n4) {
  int i = blockIdx.x * blockDim.x + threadIdx.x;
  int stride = gridDim.x * blockDim.x;
  for (; i < n4; i += stride) {
    float4 v = reinterpret_cast<const float4*>(in)[i];
    ushort4 o;
    o.x = f2bf(v.x); o.y = f2bf(v.y); o.z = f2bf(v.z); o.w = f2bf(v.w);
    reinterpret_cast<ushort4*>(out)[i] = o;
  }
}

// ---------------------------------------------------------------- projection GEMM (fused 3-way)
// grid (256, 8): blockIdx.x = 128-token tile; role = blockIdx.y.
// role 0-3: col-tile j of {k, q, gate}; role 4-7: col-tile j of {alpha, v, beta}.
// One block produces EVERY byte of the interleaved output lines it touches
// (KQi 16B groups [k0 k1 q0 q1]; AVB groups [a v beta pad]) -> no cross-block
// partial-line write amplification (was 558 MB writes, 2.8x ideal).
#define PM 128
#define PN 64
#define PK 64

__global__ void __launch_bounds__(256) proj_gemm(
    const unsigned short* __restrict__ hb, const unsigned short* __restrict__ Wc,
    const float* __restrict__ b_beta, const float* __restrict__ b_alpha,
    float* __restrict__ KQi, float* __restrict__ AVBf, float* __restrict__ gate)
{
  __shared__ unsigned short Asm[PM*PK];      // 16 KB
  __shared__ unsigned short Bsm[3][PN*PK];   // 24 KB
  const int t = threadIdx.x;
  const int w = t >> 6, lane = t & 63;
  const int bm0 = blockIdx.x * PM;
  const int role = blockIdx.y;
  const int grp = role >> 2;       // 0 = {k,q,gate}, 1 = {alpha,v,beta}
  const int bn0 = (role & 3) * 64; // column offset within each projection (0..255)
  const int pr0 = grp ? 4 : 0, pr1 = grp ? 1 : 2, pr2 = grp ? 3 : 5;

  f32x4 acc[3][2][4];
  #pragma unroll
  for (int pp = 0; pp < 3; ++pp)
    #pragma unroll
    for (int i = 0; i < 2; ++i)
      #pragma unroll
      for (int j = 0; j < 4; ++j) acc[pp][i][j] = (f32x4){0.f, 0.f, 0.f, 0.f};

  for (int k0 = 0; k0 < HID; k0 += PK) {
    // stage A: 1024 x 16B units
    #pragma unroll
    for (int it = 0; it < 4; ++it) {
      int unit = t + it * 256;
      int row = unit >> 3, seg = unit & 7;
      int dseg = seg ^ (row & 7);
      const unsigned short* g = hb + (size_t)(bm0 + row) * HID + k0 + dseg * 8;
      gload16(g, (char*)Asm + (w * 1024 + it * 4096));
    }
    // stage B for the 3 projections: 512 x 16B units each
    #pragma unroll
    for (int pp = 0; pp < 3; ++pp) {
      const int pr = (pp == 0) ? pr0 : (pp == 1) ? pr1 : pr2;
      #pragma unroll
      for (int it = 0; it < 2; ++it) {
        int unit = t + it * 256;
        int n = unit >> 3, seg = unit & 7;
        int dseg = seg ^ (n & 7);
        const unsigned short* g = Wc + (size_t)(pr * 256 + bn0 + n) * HID + k0 + dseg * 8;
        gload16(g, (char*)Bsm[pp] + (w * 1024 + it * 4096));
      }
    }
    __syncthreads();
    #pragma unroll
    for (int ks = 0; ks < 2; ++ks) {
      short8 af[2];
      int u = ks * 4 + (lane >> 4);
      int slot = u ^ (lane & 7);
      #pragma unroll
      for (int rb = 0; rb < 2; ++rb) {
        int row = w * 32 + rb * 16 + (lane & 15);
        af[rb] = *(const short8*)((const char*)Asm + row * 128 + slot * 16);
      }
      #pragma unroll
      for (int pp = 0; pp < 3; ++pp) {
        short8 bfr[4];
        #pragma unroll
        for (int cb = 0; cb < 4; ++cb) {
          int nn = cb * 16 + (lane & 15);
          bfr[cb] = *(const short8*)((const char*)Bsm[pp] + nn * 128 + slot * 16);
        }
        #pragma unroll
        for (int rb = 0; rb < 2; ++rb)
          #pragma unroll
          for (int cb = 0; cb < 4; ++cb)
            acc[pp][rb][cb] = __builtin_amdgcn_mfma_f32_16x16x32_bf16(af[rb], bfr[cb], acc[pp][rb][cb], 0, 0, 0);
      }
    }
    __syncthreads();
  }

  #pragma unroll
  for (int pp = 0; pp < 3; ++pp) {
    const int p = (pp == 0) ? pr0 : (pp == 1) ? pr1 : pr2;
    #pragma unroll
    for (int rb = 0; rb < 2; ++rb) {
      #pragma unroll
      for (int cb = 0; cb < 4; ++cb) {
        int rem = bn0 + cb * 16 + (lane & 15);   // channel within projection, 0..255
        #pragma unroll
        for (int r = 0; r < 4; ++r) {
          int m = bm0 + w * 32 + rb * 16 + (lane >> 4) * 4 + r;
          float v = acc[pp][rb][cb][r];
          int b = m >> 12, tt = m & 4095;
          int h = rem >> 5, d = rem & 31;
          size_t tok = ((size_t)(b * NH + h) * T_ + tt);
          if (p == 0) {
            KQi[tok * 64 + (d >> 1) * 4 + (d & 1)] = v;
          } else if (p == 2) {
            KQi[tok * 64 + (d >> 1) * 4 + 2 + (d & 1)] = v;
          } else if (p == 5) {
            gate[(size_t)m * SD + rem] = v;
          } else {
            float wv = v;
            if (p == 3) wv = 1.0f / (1.0f + expf(-(v + b_beta[rem])));
            if (p == 4) wv = 1.0f / (1.0f + expf(-(v + b_alpha[rem])));
            int comp = (p == 4) ? 0 : (p == 1) ? 1 : 2;   // (a, v, beta, pad)
            AVBf[(tok * HD + d) * 4 + comp] = wv;
          }
        }
      }
    }
  }
}

// ---------------------------------------------------------------- k normalization (interleaved KQ)
__global__ void __launch_bounds__(256) knorm(float* __restrict__ KQi) {
  int t = threadIdx.x;
  size_t row = (size_t)blockIdx.x * 8 + (t >> 5);
  int j = t & 31;
  int off = ((j >> 1) << 2) + (j & 1);
  float x = KQi[row * 64 + off];
  float s = x * x;
  #pragma unroll
  for (int m = 16; m >= 1; m >>= 1) s += __shfl_xor(s, m, 32);
  float inv = 1.0f / fmaxf(sqrtf(s), 1e-12f);
  KQi[row * 64 + off] = x * inv;
}

// ---------------------------------------------------------------- sequential scan
// (structure unchanged from r8 — see comments there; wave-specialized
// producer/consumer, depth-4 pipeline, exact lgkm schedule, ring offset
// PB*4096 + (T&15)*256.)
#define CH 32
#define NCH (T_/CH)

#define DSR(dst, areg, imm) \
  asm volatile("ds_read_b128 %0, %1 offset:%c2" : "=v"(dst) : "v"(areg), "i"(imm))

#define SHUF2(V,A,B) __builtin_shufflevector(V, V, A, B)

#define BAR asm volatile("s_barrier" ::: "memory")

__global__ void __launch_bounds__(128, 1) scan_kernel(
    const float* __restrict__ KQi, const float4* __restrict__ AVB,
    const float* __restrict__ state_in,
    float* __restrict__ ctx, float* __restrict__ Sfin)
{
  __shared__ __align__(16) char Lds[36864];
  const int blk = blockIdx.x;
  const int bh = blk & 63, rg = blk >> 6;
  const int b = bh >> 3, h = bh & 7;
  const int tid = threadIdx.x;
  const int wid = tid >> 6;
  const int lw = tid & 63;

  const float*  KQg = KQi + (size_t)bh * (T_ * 64);
  const float4* Vg  = AVB + (size_t)bh * (T_ * HD) + rg * 4;

  const uint32_t lds0 = (uint32_t)(uintptr_t)(__attribute__((address_space(3))) char*)&Lds[0];

  if (wid == 1) {
    // ---------------- WAVE1: producer (staging) + readout reducer ----------------
    const int il1 = lw >> 4, tq = lw & 15;
    const uint32_t a_pr = lds0 + 20480 + tq * 256 + il1 * 64;
    float* ctxb = ctx + (size_t)b * T_ * SD + h * HD + rg * 4 + il1;

    auto stageW = [&](int c2, int buf) {
      const float* kqg = KQg + (size_t)c2 * (CH * 64);
      #pragma unroll
      for (int it = 0; it < 8; ++it)
        gload16(kqg + (size_t)(lw + it * 64) * 4, Lds + buf * 8192 + it * 1024);
      const float4* vg = Vg + (size_t)c2 * (CH * HD);
      #pragma unroll
      for (int it = 0; it < 2; ++it) {
        int tc = it * 16 + (lw >> 2), r = lw & 3;
        gload16(vg + (size_t)tc * HD + r, Lds + 16384 + buf * 2048 + it * 1024);
      }
    };

#define REDUCE(PB, T0) do { \
      f4 r0_, r1_, r2_, r3_; \
      DSR(r0_, a_pr, (PB)*4096 + 0);  DSR(r1_, a_pr, (PB)*4096 + 16); \
      DSR(r2_, a_pr, (PB)*4096 + 32); DSR(r3_, a_pr, (PB)*4096 + 48); \
      asm volatile("s_waitcnt lgkmcnt(0)" : "+v"(r0_), "+v"(r1_), "+v"(r2_), "+v"(r3_)); \
      f4 s_ = (r0_ + r1_) + (r2_ + r3_); \
      float v_ = (s_.x + s_.y) + (s_.z + s_.w); \
      ctxb[(size_t)((T0) + tq) * SD] = v_; \
    } while (0)

    stageW(0, 0);
    asm volatile("s_waitcnt vmcnt(0)" ::: "memory");
    BAR;   // prologue: chunk 0 staged
    #pragma unroll 1
    for (int cp = 0; cp < NCH / 2; ++cp) {
      if (cp > 0) REDUCE(2, 64 * cp - 32);
      stageW(2 * cp + 1, 1);
      BAR;
      if (cp > 0) REDUCE(3, 64 * cp - 16);
      asm volatile("s_waitcnt vmcnt(0)" ::: "memory");
      BAR;
      REDUCE(0, 64 * cp);
      if (cp < NCH / 2 - 1) stageW(2 * cp + 2, 0);
      BAR;
      REDUCE(1, 64 * cp + 16);
      asm volatile("s_waitcnt vmcnt(0)" ::: "memory");
      BAR;
    }
    BAR;  // final sync (wave0 drained its last partial writes)
    REDUCE(2, T_ - 32);
    REDUCE(3, T_ - 16);
#undef REDUCE
    return;
  }

  // ---------------- WAVE0: the sequential recurrence ----------------
  const int il = lw >> 4;    // local row
  const int p  = lw & 15;    // column part (cols 2p, 2p+1)

  f2 S2;
  {
    const float* sp = state_in + (size_t)bh * 1024 + (rg * 4 + il) * 32 + p * 2;
    S2 = (f2){sp[0], sp[1]};
  }

  const uint32_t a_kq = lds0 + p * 16;
  const uint32_t a_v  = lds0 + 16384 + il * 16;
  const uint32_t a_pw = lds0 + 20480 + lw * 4;

#define C1(S, T, PB) do { \
    f2 k2_ = SHUF2(kq##S, 0, 1); \
    f2 q2_ = SHUF2(kq##S, 2, 3); \
    f4 VV_ = vv##S; \
    f2 as_ = (f2){VV_.x, VV_.x} * S2; \
    f2 d_  = k2_ * S2; \
    float pd_ = qred16(d_.x + d_.y); \
    float bv_ = VV_.y * VV_.z, ba_ = VV_.x * VV_.z; \
    float u_ = fmaf(-ba_, pd_, bv_); \
    S2 = __builtin_elementwise_fma((f2){u_, u_}, k2_, as_); \
    f2 o_ = q2_ * S2; \
    float po_ = o_.x + o_.y; \
    asm volatile("ds_write_b32 %0, %1 offset:%c2" :: "v"(a_pw), "v"(po_), "i"((PB)*4096 + ((T)&15)*256)); \
  } while (0)

  f4 kqA, vvA, kqB, vvB, kqC, vvC, kqD, vvD;

#define R1(S, BUF, T) do { \
    DSR(kq##S, a_kq, (BUF)*8192 + (T)*256); \
    DSR(vv##S, a_v,  (BUF)*2048 + (T)*64); \
  } while (0)

#define WKA(N, S) \
    asm volatile("s_waitcnt lgkmcnt(" #N ")" : "+v"(kq##S), "+v"(vv##S))

#define CHUNK(BUF, PBa, PBb) do { \
    R1(A,BUF,0); R1(B,BUF,1); R1(C,BUF,2); R1(D,BUF,3); \
    WKA(6,A); C1(A, 0,PBa); R1(A,BUF, 4); \
    WKA(7,B); C1(B, 1,PBa); R1(B,BUF, 5); \
    WKA(8,C); C1(C, 2,PBa); R1(C,BUF, 6); \
    WKA(9,D); C1(D, 3,PBa); R1(D,BUF, 7); \
    WKA(9,A); C1(A, 4,PBa); R1(A,BUF, 8); \
    WKA(9,B); C1(B, 5,PBa); R1(B,BUF, 9); \
    WKA(9,C); C1(C, 6,PBa); R1(C,BUF,10); \
    WKA(9,D); C1(D, 7,PBa); R1(D,BUF,11); \
    WKA(9,A); C1(A, 8,PBa); R1(A,BUF,12); \
    WKA(9,B); C1(B, 9,PBa); R1(B,BUF,13); \
    WKA(9,C); C1(C,10,PBa); R1(C,BUF,14); \
    WKA(9,D); C1(D,11,PBa); R1(D,BUF,15); \
    WKA(9,A); C1(A,12,PBa); R1(A,BUF,16); \
    WKA(9,B); C1(B,13,PBa); R1(B,BUF,17); \
    WKA(9,C); C1(C,14,PBa); R1(C,BUF,18); \
    WKA(9,D); C1(D,15,PBa); R1(D,BUF,19); \
    BAR; \
    WKA(9,A); C1(A,16,PBb); R1(A,BUF,20); \
    WKA(9,B); C1(B,17,PBb); R1(B,BUF,21); \
    WKA(9,C); C1(C,18,PBb); R1(C,BUF,22); \
    WKA(9,D); C1(D,19,PBb); R1(D,BUF,23); \
    WKA(9,A); C1(A,20,PBb); R1(A,BUF,24); \
    WKA(9,B); C1(B,21,PBb); R1(B,BUF,25); \
    WKA(9,C); C1(C,22,PBb); R1(C,BUF,26); \
    WKA(9,D); C1(D,23,PBb); R1(D,BUF,27); \
    WKA(9,A); C1(A,24,PBb); R1(A,BUF,28); \
    WKA(9,B); C1(B,25,PBb); R1(B,BUF,29); \
    WKA(9,C); C1(C,26,PBb); R1(C,BUF,30); \
    WKA(9,D); C1(D,27,PBb); R1(D,BUF,31); \
    WKA(9,A); C1(A,28,PBb); \
    WKA(7,B); C1(B,29,PBb); \
    WKA(5,C); C1(C,30,PBb); \
    WKA(3,D); C1(D,31,PBb); \
    BAR; \
  } while (0)

  BAR;   // prologue: wait for wave1's stage(0)
  #pragma unroll 1
  for (int cp = 0; cp < NCH / 2; ++cp) {
    CHUNK(0, 0, 1);
    CHUNK(1, 2, 3);
  }
  asm volatile("s_waitcnt lgkmcnt(0)" ::: "memory");
  BAR;   // final: partial writes of last group now visible/retired

  {
    float* sp = Sfin + (size_t)bh * 1024 + (rg * 4 + il) * 32 + p * 2;
    sp[0] = S2.x; sp[1] = S2.y;
  }
#undef C1
#undef R1
#undef WKA
#undef CHUNK
}

// ---------------------------------------------------------------- rmsnorm * silu(gate) -> bf16
__global__ void __launch_bounds__(256) rms_silu(
    const float* __restrict__ ctx, const float* __restrict__ gate,
    const float* __restrict__ norm_w, unsigned short* __restrict__ ctx2)
{
  size_t row = (size_t)blockIdx.x * 4 + (threadIdx.x >> 6);
  int lane = threadIdx.x & 63;
  const float4 x = *(const float4*)&ctx[row * SD + lane * 4];
  float s = x.x * x.x + x.y * x.y + x.z * x.z + x.w * x.w;
  #pragma unroll
  for (int m = 32; m >= 1; m >>= 1) s += __shfl_xor(s, m, 64);
  float rs = 1.0f / sqrtf(s * (1.0f / 256.0f) + 1e-6f);
  const float4 g = *(const float4*)&gate[row * SD + lane * 4];
  const float4 w = *(const float4*)&norm_w[lane * 4];
  ushort4 o;
  o.x = f2bf(x.x * rs * w.x * (g.x / (1.0f + expf(-g.x))));
  o.y = f2bf(x.y * rs * w.y * (g.y / (1.0f + expf(-g.y))));
  o.z = f2bf(x.z * rs * w.z * (g.z / (1.0f + expf(-g.z))));
  o.w = f2bf(x.w * rs * w.w * (g.w / (1.0f + expf(-g.w))));
  *(ushort4*)&ctx2[row * SD + lane * 4] = o;
}

// ---------------------------------------------------------------- output GEMM
__global__ void __launch_bounds__(256) out_gemm(
    const unsigned short* __restrict__ ctx2, const unsigned short* __restrict__ Wob,
    float* __restrict__ out)
{
  __shared__ unsigned short Asm[PM*PK];
  __shared__ unsigned short Bsm[PN*PK];
  const int t = threadIdx.x;
  const int w = t >> 6, lane = t & 63;
  const int bm0 = blockIdx.x * PM;
  const int bn0 = blockIdx.y * PN;

  f32x4 acc[2][4];
  #pragma unroll
  for (int i = 0; i < 2; ++i)
    #pragma unroll
    for (int j = 0; j < 4; ++j) acc[i][j] = (f32x4){0.f, 0.f, 0.f, 0.f};

  for (int k0 = 0; k0 < SD; k0 += PK) {
    #pragma unroll
    for (int it = 0; it < 4; ++it) {
      int unit = t + it * 256;
      int row = unit >> 3, seg = unit & 7;
      int dseg = seg ^ (row & 7);
      const unsigned short* g = ctx2 + (size_t)(bm0 + row) * SD + k0 + dseg * 8;
      gload16(g, (char*)Asm + (w * 1024 + it * 4096));
    }
    #pragma unroll
    for (int it = 0; it < 2; ++it) {
      int unit = t + it * 256;
      int n = unit >> 3, seg = unit & 7;
      int dseg = seg ^ (n & 7);
      const unsigned short* g = Wob + (size_t)(bn0 + n) * SD + k0 + dseg * 8;
      gload16(g, (char*)Bsm + (w * 1024 + it * 4096));
    }
    __syncthreads();
    #pragma unroll
    for (int ks = 0; ks < 2; ++ks) {
      short8 af[2], bfr[4];
      int u = ks * 4 + (lane >> 4);
      int slot = u ^ (lane & 7);
      #pragma unroll
      for (int rb = 0; rb < 2; ++rb) {
        int row = w * 32 + rb * 16 + (lane & 15);
        af[rb] = *(const short8*)((const char*)Asm + row * 128 + slot * 16);
      }
      #pragma unroll
      for (int cb = 0; cb < 4; ++cb) {
        int nn = cb * 16 + (lane & 15);
        bfr[cb] = *(const short8*)((const char*)Bsm + nn * 128 + slot * 16);
      }
      #pragma unroll
      for (int rb = 0; rb < 2; ++rb)
        #pragma unroll
        for (int cb = 0; cb < 4; ++cb)
          acc[rb][cb] = __builtin_amdgcn_mfma_f32_16x16x32_bf16(af[rb], bfr[cb], acc[rb][cb], 0, 0, 0);
    }
    __syncthreads();
  }
  #pragma unroll
  for (int rb = 0; rb < 2; ++rb)
    #pragma unroll
    for (int cb = 0; cb < 4; ++cb) {
      int n = bn0 + cb * 16 + (lane & 15);
      #pragma unroll
      for (int r = 0; r < 4; ++r) {
        int m = bm0 + w * 32 + rb * 16 + (lane >> 4) * 4 + r;
        out[(size_t)m * 512 + n] = acc[rb][cb][r];
      }
    }
}

// ---------------------------------------------------------------- launcher
// ws layout (bytes), total 253,493,248:
//   hb   bf16 [32768][512]            @ 0
//   Wc   bf16 [1536][512]             @ 33,554,432
//   Wob  bf16 [512][256]              @ 35,127,296
//   KQi  f32  [64][4096][64]          @ 35,389,440   (16 groups x [k0 k1 q0 q1])
//   AVB  f32x4 [64][4096][32]         @ 102,498,304  (a, v, beta, pad)
//   ctx2 bf16 [32768][256]            @ 236,716,032
// d_out reuse: ctx f32 [32768][256] @ 0; gate f32 [32768][256] @ +8388608 floats
// (both overwritten later by out_gemm); Sfin @ +16777216 floats.
extern "C" void kernel_launch(void* const* d_in, const int* in_sizes, int n_in,
                              void* d_out, int out_size, void* d_ws, size_t ws_size,
                              hipStream_t stream) {
  (void)in_sizes; (void)n_in; (void)out_size; (void)ws_size;
  const float* hidden  = (const float*)d_in[0];
  const float* state   = (const float*)d_in[1];
  const float* W_k     = (const float*)d_in[2];
  const float* W_v     = (const float*)d_in[3];
  const float* W_q     = (const float*)d_in[4];
  const float* W_beta  = (const float*)d_in[5];
  const float* b_beta  = (const float*)d_in[6];
  const float* W_alpha = (const float*)d_in[7];
  const float* b_alpha = (const float*)d_in[8];
  const float* W_out   = (const float*)d_in[9];
  const float* gate_W  = (const float*)d_in[10];
  const float* norm_w  = (const float*)d_in[11];
  float* out = (float*)d_out;

  char* ws = (char*)d_ws;
  unsigned short* hb  = (unsigned short*)(ws);
  unsigned short* Wc  = (unsigned short*)(ws + 33554432);
  unsigned short* Wob = (unsigned short*)(ws + 35127296);
  float* KQi  = (float*)(ws + 35389440);
  float* AVBf = (float*)(ws + 102498304);
  unsigned short* ctx2 = (unsigned short*)(ws + 236716032);
  float* ctx  = out;                 // fp32 scratch, overwritten by out_gemm
  float* gate = out + 8388608;       // fp32 scratch, overwritten by out_gemm
  float* Sfin = out + 16777216;      // final state output

  cvt_f32_bf16<<<2048, 256, 0, stream>>>(hidden, hb, M_TOK * HID / 4);
  cvt_f32_bf16<<<64, 256, 0, stream>>>(W_k,     Wc + 0 * 131072, 32768);
  cvt_f32_bf16<<<64, 256, 0, stream>>>(W_v,     Wc + 1 * 131072, 32768);
  cvt_f32_bf16<<<64, 256, 0, stream>>>(W_q,     Wc + 2 * 131072, 32768);
  cvt_f32_bf16<<<64, 256, 0, stream>>>(W_beta,  Wc + 3 * 131072, 32768);
  cvt_f32_bf16<<<64, 256, 0, stream>>>(W_alpha, Wc + 4 * 131072, 32768);
  cvt_f32_bf16<<<64, 256, 0, stream>>>(gate_W,  Wc + 5 * 131072, 32768);
  cvt_f32_bf16<<<64, 256, 0, stream>>>(W_out,   Wob, 32768);

  proj_gemm<<<dim3(256, 8), 256, 0, stream>>>(hb, Wc, b_beta, b_alpha, KQi, AVBf, gate);
  knorm<<<32768, 256, 0, stream>>>(KQi);
  scan_kernel<<<512, 128, 0, stream>>>(KQi, (const float4*)AVBf, state, ctx, Sfin);
  rms_silu<<<8192, 256, 0, stream>>>(ctx, gate, norm_w, ctx2);
  out_gemm<<<dim3(256, 8), 256, 0, stream>>>(ctx2, Wob, out);
}

// Round 10
// 450.058 us; speedup vs baseline: 1.4141x; 1.1277x over previous
//
#include <hip/hip_runtime.h>
#include <stdint.h>

// Problem constants
#define B_    8
#define T_    4096
#define HID   512
#define SD    256
#define NH    8
#define HD    32
#define M_TOK (B_*T_)          // 32768 tokens
#define NPROJ 1536             // 6 * 256 output channels (k,v,q,beta,alpha,gate)

typedef __attribute__((ext_vector_type(8))) short short8;   // 8 bf16 (4 VGPRs) — MFMA A/B frag
typedef __attribute__((ext_vector_type(4))) float f32x4;    // MFMA C/D frag
typedef __attribute__((ext_vector_type(4))) float f4;       // asm ds_read_b128 dst
typedef __attribute__((ext_vector_type(2))) float f2;       // packed fp32 (v_pk_*_f32)

__device__ __forceinline__ unsigned short f2bf(float f) {
  uint32_t u = __float_as_uint(f);
  uint32_t r = (u + 0x7fffu + ((u >> 16) & 1u)) >> 16;
  return (unsigned short)r;
}

__device__ __forceinline__ void gload16(const void* g, void* l) {
  // async global->LDS, 16B per lane; LDS dest = wave-uniform base + lane*16
  __builtin_amdgcn_global_load_lds((const __attribute__((address_space(1))) void*)g,
                                   (__attribute__((address_space(3))) void*)l,
                                   16, 0, 0);
}

// butterfly sum across 16 consecutive lanes (one DPP row) — pure VALU, no DS.
__device__ __forceinline__ float qred16(float x) {
  x += __int_as_float(__builtin_amdgcn_mov_dpp(__float_as_int(x), 0xB1,  0xF, 0xF, true));
  x += __int_as_float(__builtin_amdgcn_mov_dpp(__float_as_int(x), 0x4E,  0xF, 0xF, true));
  x += __int_as_float(__builtin_amdgcn_mov_dpp(__float_as_int(x), 0x141, 0xF, 0xF, true));
  x += __int_as_float(__builtin_amdgcn_mov_dpp(__float_as_int(x), 0x128, 0xF, 0xF, true));
  return x;
}

// value of lane^1 (quad_perm [1,0,3,2]) — pure VALU
__device__ __forceinline__ float dpp_xor1(float x) {
  return __int_as_float(__builtin_amdgcn_mov_dpp(__float_as_int(x), 0xB1, 0xF, 0xF, true));
}

// ---------------------------------------------------------------- converts
__global__ void cvt_f32_bf16(const float* __restrict__ in, unsigned short* __restrict__ out, int n4) {
  int i = blockIdx.x * blockDim.x + threadIdx.x;
  int stride = gridDim.x * blockDim.x;
  for (; i < n4; i += stride) {
    float4 v = reinterpret_cast<const float4*>(in)[i];
    ushort4 o;
    o.x = f2bf(v.x); o.y = f2bf(v.y); o.z = f2bf(v.z); o.w = f2bf(v.w);
    reinterpret_cast<ushort4*>(out)[i] = o;
  }
}

// ---------------------------------------------------------------- projection GEMM (fused 3-way)
// grid (256, 8): blockIdx.x = 128-token tile; role = blockIdx.y.
// role 0-3: col-tile j of {k, q, gate}; role 4-7: col-tile j of {alpha, v, beta}.
// Epilogue writes FULL 16B groups per store (KQi via lane^1 DPP pair-exchange,
// even lanes store float4 {k0,k1,q0,q1}; AVB one float4 {a,v,b,0} per lane) —
// eliminates the 2.4x partial-sector write amplification (553 -> ~235 MB).
// k-normalization fused in-register (16-lane qred16 per token-half) — knorm
// kernel eliminated.
#define PM 128
#define PN 64
#define PK 64

__global__ void __launch_bounds__(256) proj_gemm(
    const unsigned short* __restrict__ hb, const unsigned short* __restrict__ Wc,
    const float* __restrict__ b_beta, const float* __restrict__ b_alpha,
    float* __restrict__ KQi, float* __restrict__ AVBf, float* __restrict__ gate)
{
  __shared__ unsigned short Asm[PM*PK];      // 16 KB
  __shared__ unsigned short Bsm[3][PN*PK];   // 24 KB
  const int t = threadIdx.x;
  const int w = t >> 6, lane = t & 63;
  const int bm0 = blockIdx.x * PM;
  const int role = blockIdx.y;
  const int grp = role >> 2;       // 0 = {k,q,gate}, 1 = {alpha,v,beta}
  const int bn0 = (role & 3) * 64; // column offset within each projection (0..255)
  const int pr0 = grp ? 4 : 0, pr1 = grp ? 1 : 2, pr2 = grp ? 3 : 5;

  f32x4 acc[3][2][4];
  #pragma unroll
  for (int pp = 0; pp < 3; ++pp)
    #pragma unroll
    for (int i = 0; i < 2; ++i)
      #pragma unroll
      for (int j = 0; j < 4; ++j) acc[pp][i][j] = (f32x4){0.f, 0.f, 0.f, 0.f};

  for (int k0 = 0; k0 < HID; k0 += PK) {
    // stage A: 1024 x 16B units
    #pragma unroll
    for (int it = 0; it < 4; ++it) {
      int unit = t + it * 256;
      int row = unit >> 3, seg = unit & 7;
      int dseg = seg ^ (row & 7);
      const unsigned short* g = hb + (size_t)(bm0 + row) * HID + k0 + dseg * 8;
      gload16(g, (char*)Asm + (w * 1024 + it * 4096));
    }
    // stage B for the 3 projections: 512 x 16B units each
    #pragma unroll
    for (int pp = 0; pp < 3; ++pp) {
      const int pr = (pp == 0) ? pr0 : (pp == 1) ? pr1 : pr2;
      #pragma unroll
      for (int it = 0; it < 2; ++it) {
        int unit = t + it * 256;
        int n = unit >> 3, seg = unit & 7;
        int dseg = seg ^ (n & 7);
        const unsigned short* g = Wc + (size_t)(pr * 256 + bn0 + n) * HID + k0 + dseg * 8;
        gload16(g, (char*)Bsm[pp] + (w * 1024 + it * 4096));
      }
    }
    __syncthreads();
    #pragma unroll
    for (int ks = 0; ks < 2; ++ks) {
      short8 af[2];
      int u = ks * 4 + (lane >> 4);
      int slot = u ^ (lane & 7);
      #pragma unroll
      for (int rb = 0; rb < 2; ++rb) {
        int row = w * 32 + rb * 16 + (lane & 15);
        af[rb] = *(const short8*)((const char*)Asm + row * 128 + slot * 16);
      }
      #pragma unroll
      for (int pp = 0; pp < 3; ++pp) {
        short8 bfr[4];
        #pragma unroll
        for (int cb = 0; cb < 4; ++cb) {
          int nn = cb * 16 + (lane & 15);
          bfr[cb] = *(const short8*)((const char*)Bsm[pp] + nn * 128 + slot * 16);
        }
        #pragma unroll
        for (int rb = 0; rb < 2; ++rb)
          #pragma unroll
          for (int cb = 0; cb < 4; ++cb)
            acc[pp][rb][cb] = __builtin_amdgcn_mfma_f32_16x16x32_bf16(af[rb], bfr[cb], acc[pp][rb][cb], 0, 0, 0);
      }
    }
    __syncthreads();
  }

  if (grp == 0) {
    // ---- fused k-normalization: acc[0] holds k; a 16-lane DPP row covers all
    // 32 d-channels of one (m, h): cb 0/1 -> h0, cb 2/3 -> h1.
    #pragma unroll
    for (int rb = 0; rb < 2; ++rb) {
      #pragma unroll
      for (int r = 0; r < 4; ++r) {
        float s0 = acc[0][rb][0][r] * acc[0][rb][0][r] + acc[0][rb][1][r] * acc[0][rb][1][r];
        float s1 = acc[0][rb][2][r] * acc[0][rb][2][r] + acc[0][rb][3][r] * acc[0][rb][3][r];
        s0 = qred16(s0); s1 = qred16(s1);
        float i0 = 1.0f / fmaxf(sqrtf(s0), 1e-12f);
        float i1 = 1.0f / fmaxf(sqrtf(s1), 1e-12f);
        acc[0][rb][0][r] *= i0; acc[0][rb][1][r] *= i0;
        acc[0][rb][2][r] *= i1; acc[0][rb][3][r] *= i1;
      }
    }
    // ---- stores: even lanes write full KQi 16B group {k0,k1,q0,q1}
    #pragma unroll
    for (int rb = 0; rb < 2; ++rb) {
      #pragma unroll
      for (int cb = 0; cb < 4; ++cb) {
        int rem = bn0 + cb * 16 + (lane & 15);
        int h = rem >> 5, d = rem & 31;
        #pragma unroll
        for (int r = 0; r < 4; ++r) {
          int m = bm0 + w * 32 + rb * 16 + (lane >> 4) * 4 + r;
          int bb = m >> 12, tt = m & 4095;
          size_t tok = ((size_t)(bb * NH + h) * T_ + tt);
          float kv = acc[0][rb][cb][r], qv = acc[1][rb][cb][r];
          float kn = dpp_xor1(kv), qn = dpp_xor1(qv);
          if ((lane & 1) == 0)
            *(float4*)&KQi[tok * 64 + (d >> 1) * 4] = (float4){kv, kn, qv, qn};
          gate[(size_t)m * SD + rem] = acc[2][rb][cb][r];
        }
      }
    }
  } else {
    // ---- stores: one full 16B AVB group {alpha, v, beta, 0} per lane
    #pragma unroll
    for (int rb = 0; rb < 2; ++rb) {
      #pragma unroll
      for (int cb = 0; cb < 4; ++cb) {
        int rem = bn0 + cb * 16 + (lane & 15);
        int h = rem >> 5, d = rem & 31;
        #pragma unroll
        for (int r = 0; r < 4; ++r) {
          int m = bm0 + w * 32 + rb * 16 + (lane >> 4) * 4 + r;
          int bb = m >> 12, tt = m & 4095;
          size_t tok = ((size_t)(bb * NH + h) * T_ + tt);
          float av = 1.0f / (1.0f + expf(-(acc[0][rb][cb][r] + b_alpha[rem])));
          float vv = acc[1][rb][cb][r];
          float bv = 1.0f / (1.0f + expf(-(acc[2][rb][cb][r] + b_beta[rem])));
          *(float4*)&AVBf[(tok * HD + d) * 4] = (float4){av, vv, bv, 0.0f};
        }
      }
    }
  }
}

// ---------------------------------------------------------------- sequential scan
// (structure unchanged from r8 — wave-specialized producer/consumer, depth-4
// pipeline, exact lgkm schedule, ring offset PB*4096 + (T&15)*256.)
#define CH 32
#define NCH (T_/CH)

#define DSR(dst, areg, imm) \
  asm volatile("ds_read_b128 %0, %1 offset:%c2" : "=v"(dst) : "v"(areg), "i"(imm))

#define SHUF2(V,A,B) __builtin_shufflevector(V, V, A, B)

#define BAR asm volatile("s_barrier" ::: "memory")

__global__ void __launch_bounds__(128, 1) scan_kernel(
    const float* __restrict__ KQi, const float4* __restrict__ AVB,
    const float* __restrict__ state_in,
    float* __restrict__ ctx, float* __restrict__ Sfin)
{
  __shared__ __align__(16) char Lds[36864];
  const int blk = blockIdx.x;
  const int bh = blk & 63, rg = blk >> 6;
  const int b = bh >> 3, h = bh & 7;
  const int tid = threadIdx.x;
  const int wid = tid >> 6;
  const int lw = tid & 63;

  const float*  KQg = KQi + (size_t)bh * (T_ * 64);
  const float4* Vg  = AVB + (size_t)bh * (T_ * HD) + rg * 4;

  const uint32_t lds0 = (uint32_t)(uintptr_t)(__attribute__((address_space(3))) char*)&Lds[0];

  if (wid == 1) {
    // ---------------- WAVE1: producer (staging) + readout reducer ----------------
    const int il1 = lw >> 4, tq = lw & 15;
    const uint32_t a_pr = lds0 + 20480 + tq * 256 + il1 * 64;
    float* ctxb = ctx + (size_t)b * T_ * SD + h * HD + rg * 4 + il1;

    auto stageW = [&](int c2, int buf) {
      const float* kqg = KQg + (size_t)c2 * (CH * 64);
      #pragma unroll
      for (int it = 0; it < 8; ++it)
        gload16(kqg + (size_t)(lw + it * 64) * 4, Lds + buf * 8192 + it * 1024);
      const float4* vg = Vg + (size_t)c2 * (CH * HD);
      #pragma unroll
      for (int it = 0; it < 2; ++it) {
        int tc = it * 16 + (lw >> 2), r = lw & 3;
        gload16(vg + (size_t)tc * HD + r, Lds + 16384 + buf * 2048 + it * 1024);
      }
    };

#define REDUCE(PB, T0) do { \
      f4 r0_, r1_, r2_, r3_; \
      DSR(r0_, a_pr, (PB)*4096 + 0);  DSR(r1_, a_pr, (PB)*4096 + 16); \
      DSR(r2_, a_pr, (PB)*4096 + 32); DSR(r3_, a_pr, (PB)*4096 + 48); \
      asm volatile("s_waitcnt lgkmcnt(0)" : "+v"(r0_), "+v"(r1_), "+v"(r2_), "+v"(r3_)); \
      f4 s_ = (r0_ + r1_) + (r2_ + r3_); \
      float v_ = (s_.x + s_.y) + (s_.z + s_.w); \
      ctxb[(size_t)((T0) + tq) * SD] = v_; \
    } while (0)

    stageW(0, 0);
    asm volatile("s_waitcnt vmcnt(0)" ::: "memory");
    BAR;   // prologue: chunk 0 staged
    #pragma unroll 1
    for (int cp = 0; cp < NCH / 2; ++cp) {
      if (cp > 0) REDUCE(2, 64 * cp - 32);
      stageW(2 * cp + 1, 1);
      BAR;
      if (cp > 0) REDUCE(3, 64 * cp - 16);
      asm volatile("s_waitcnt vmcnt(0)" ::: "memory");
      BAR;
      REDUCE(0, 64 * cp);
      if (cp < NCH / 2 - 1) stageW(2 * cp + 2, 0);
      BAR;
      REDUCE(1, 64 * cp + 16);
      asm volatile("s_waitcnt vmcnt(0)" ::: "memory");
      BAR;
    }
    BAR;  // final sync (wave0 drained its last partial writes)
    REDUCE(2, T_ - 32);
    REDUCE(3, T_ - 16);
#undef REDUCE
    return;
  }

  // ---------------- WAVE0: the sequential recurrence ----------------
  const int il = lw >> 4;    // local row
  const int p  = lw & 15;    // column part (cols 2p, 2p+1)

  f2 S2;
  {
    const float* sp = state_in + (size_t)bh * 1024 + (rg * 4 + il) * 32 + p * 2;
    S2 = (f2){sp[0], sp[1]};
  }

  const uint32_t a_kq = lds0 + p * 16;
  const uint32_t a_v  = lds0 + 16384 + il * 16;
  const uint32_t a_pw = lds0 + 20480 + lw * 4;

#define C1(S, T, PB) do { \
    f2 k2_ = SHUF2(kq##S, 0, 1); \
    f2 q2_ = SHUF2(kq##S, 2, 3); \
    f4 VV_ = vv##S; \
    f2 as_ = (f2){VV_.x, VV_.x} * S2; \
    f2 d_  = k2_ * S2; \
    float pd_ = qred16(d_.x + d_.y); \
    float bv_ = VV_.y * VV_.z, ba_ = VV_.x * VV_.z; \
    float u_ = fmaf(-ba_, pd_, bv_); \
    S2 = __builtin_elementwise_fma((f2){u_, u_}, k2_, as_); \
    f2 o_ = q2_ * S2; \
    float po_ = o_.x + o_.y; \
    asm volatile("ds_write_b32 %0, %1 offset:%c2" :: "v"(a_pw), "v"(po_), "i"((PB)*4096 + ((T)&15)*256)); \
  } while (0)

  f4 kqA, vvA, kqB, vvB, kqC, vvC, kqD, vvD;

#define R1(S, BUF, T) do { \
    DSR(kq##S, a_kq, (BUF)*8192 + (T)*256); \
    DSR(vv##S, a_v,  (BUF)*2048 + (T)*64); \
  } while (0)

#define WKA(N, S) \
    asm volatile("s_waitcnt lgkmcnt(" #N ")" : "+v"(kq##S), "+v"(vv##S))

#define CHUNK(BUF, PBa, PBb) do { \
    R1(A,BUF,0); R1(B,BUF,1); R1(C,BUF,2); R1(D,BUF,3); \
    WKA(6,A); C1(A, 0,PBa); R1(A,BUF, 4); \
    WKA(7,B); C1(B, 1,PBa); R1(B,BUF, 5); \
    WKA(8,C); C1(C, 2,PBa); R1(C,BUF, 6); \
    WKA(9,D); C1(D, 3,PBa); R1(D,BUF, 7); \
    WKA(9,A); C1(A, 4,PBa); R1(A,BUF, 8); \
    WKA(9,B); C1(B, 5,PBa); R1(B,BUF, 9); \
    WKA(9,C); C1(C, 6,PBa); R1(C,BUF,10); \
    WKA(9,D); C1(D, 7,PBa); R1(D,BUF,11); \
    WKA(9,A); C1(A, 8,PBa); R1(A,BUF,12); \
    WKA(9,B); C1(B, 9,PBa); R1(B,BUF,13); \
    WKA(9,C); C1(C,10,PBa); R1(C,BUF,14); \
    WKA(9,D); C1(D,11,PBa); R1(D,BUF,15); \
    WKA(9,A); C1(A,12,PBa); R1(A,BUF,16); \
    WKA(9,B); C1(B,13,PBa); R1(B,BUF,17); \
    WKA(9,C); C1(C,14,PBa); R1(C,BUF,18); \
    WKA(9,D); C1(D,15,PBa); R1(D,BUF,19); \
    BAR; \
    WKA(9,A); C1(A,16,PBb); R1(A,BUF,20); \
    WKA(9,B); C1(B,17,PBb); R1(B,BUF,21); \
    WKA(9,C); C1(C,18,PBb); R1(C,BUF,22); \
    WKA(9,D); C1(D,19,PBb); R1(D,BUF,23); \
    WKA(9,A); C1(A,20,PBb); R1(A,BUF,24); \
    WKA(9,B); C1(B,21,PBb); R1(B,BUF,25); \
    WKA(9,C); C1(C,22,PBb); R1(C,BUF,26); \
    WKA(9,D); C1(D,23,PBb); R1(D,BUF,27); \
    WKA(9,A); C1(A,24,PBb); R1(A,BUF,28); \
    WKA(9,B); C1(B,25,PBb); R1(B,BUF,29); \
    WKA(9,C); C1(C,26,PBb); R1(C,BUF,30); \
    WKA(9,D); C1(D,27,PBb); R1(D,BUF,31); \
    WKA(9,A); C1(A,28,PBb); \
    WKA(7,B); C1(B,29,PBb); \
    WKA(5,C); C1(C,30,PBb); \
    WKA(3,D); C1(D,31,PBb); \
    BAR; \
  } while (0)

  BAR;   // prologue: wait for wave1's stage(0)
  #pragma unroll 1
  for (int cp = 0; cp < NCH / 2; ++cp) {
    CHUNK(0, 0, 1);
    CHUNK(1, 2, 3);
  }
  asm volatile("s_waitcnt lgkmcnt(0)" ::: "memory");
  BAR;   // final: partial writes of last group now visible/retired

  {
    float* sp = Sfin + (size_t)bh * 1024 + (rg * 4 + il) * 32 + p * 2;
    sp[0] = S2.x; sp[1] = S2.y;
  }
#undef C1
#undef R1
#undef WKA
#undef CHUNK
}

// ---------------------------------------------------------------- rmsnorm * silu(gate) -> bf16
__global__ void __launch_bounds__(256) rms_silu(
    const float* __restrict__ ctx, const float* __restrict__ gate,
    const float* __restrict__ norm_w, unsigned short* __restrict__ ctx2)
{
  size_t row = (size_t)blockIdx.x * 4 + (threadIdx.x >> 6);
  int lane = threadIdx.x & 63;
  const float4 x = *(const float4*)&ctx[row * SD + lane * 4];
  float s = x.x * x.x + x.y * x.y + x.z * x.z + x.w * x.w;
  #pragma unroll
  for (int m = 32; m >= 1; m >>= 1) s += __shfl_xor(s, m, 64);
  float rs = 1.0f / sqrtf(s * (1.0f / 256.0f) + 1e-6f);
  const float4 g = *(const float4*)&gate[row * SD + lane * 4];
  const float4 w = *(const float4*)&norm_w[lane * 4];
  ushort4 o;
  o.x = f2bf(x.x * rs * w.x * (g.x / (1.0f + expf(-g.x))));
  o.y = f2bf(x.y * rs * w.y * (g.y / (1.0f + expf(-g.y))));
  o.z = f2bf(x.z * rs * w.z * (g.z / (1.0f + expf(-g.z))));
  o.w = f2bf(x.w * rs * w.w * (g.w / (1.0f + expf(-g.w))));
  *(ushort4*)&ctx2[row * SD + lane * 4] = o;
}

// ---------------------------------------------------------------- output GEMM
__global__ void __launch_bounds__(256) out_gemm(
    const unsigned short* __restrict__ ctx2, const unsigned short* __restrict__ Wob,
    float* __restrict__ out)
{
  __shared__ unsigned short Asm[PM*PK];
  __shared__ unsigned short Bsm[PN*PK];
  const int t = threadIdx.x;
  const int w = t >> 6, lane = t & 63;
  const int bm0 = blockIdx.x * PM;
  const int bn0 = blockIdx.y * PN;

  f32x4 acc[2][4];
  #pragma unroll
  for (int i = 0; i < 2; ++i)
    #pragma unroll
    for (int j = 0; j < 4; ++j) acc[i][j] = (f32x4){0.f, 0.f, 0.f, 0.f};

  for (int k0 = 0; k0 < SD; k0 += PK) {
    #pragma unroll
    for (int it = 0; it < 4; ++it) {
      int unit = t + it * 256;
      int row = unit >> 3, seg = unit & 7;
      int dseg = seg ^ (row & 7);
      const unsigned short* g = ctx2 + (size_t)(bm0 + row) * SD + k0 + dseg * 8;
      gload16(g, (char*)Asm + (w * 1024 + it * 4096));
    }
    #pragma unroll
    for (int it = 0; it < 2; ++it) {
      int unit = t + it * 256;
      int n = unit >> 3, seg = unit & 7;
      int dseg = seg ^ (n & 7);
      const unsigned short* g = Wob + (size_t)(bn0 + n) * SD + k0 + dseg * 8;
      gload16(g, (char*)Bsm + (w * 1024 + it * 4096));
    }
    __syncthreads();
    #pragma unroll
    for (int ks = 0; ks < 2; ++ks) {
      short8 af[2], bfr[4];
      int u = ks * 4 + (lane >> 4);
      int slot = u ^ (lane & 7);
      #pragma unroll
      for (int rb = 0; rb < 2; ++rb) {
        int row = w * 32 + rb * 16 + (lane & 15);
        af[rb] = *(const short8*)((const char*)Asm + row * 128 + slot * 16);
      }
      #pragma unroll
      for (int cb = 0; cb < 4; ++cb) {
        int nn = cb * 16 + (lane & 15);
        bfr[cb] = *(const short8*)((const char*)Bsm + nn * 128 + slot * 16);
      }
      #pragma unroll
      for (int rb = 0; rb < 2; ++rb)
        #pragma unroll
        for (int cb = 0; cb < 4; ++cb)
          acc[rb][cb] = __builtin_amdgcn_mfma_f32_16x16x32_bf16(af[rb], bfr[cb], acc[rb][cb], 0, 0, 0);
    }
    __syncthreads();
  }
  #pragma unroll
  for (int rb = 0; rb < 2; ++rb)
    #pragma unroll
    for (int cb = 0; cb < 4; ++cb) {
      int n = bn0 + cb * 16 + (lane & 15);
      #pragma unroll
      for (int r = 0; r < 4; ++r) {
        int m = bm0 + w * 32 + rb * 16 + (lane >> 4) * 4 + r;
        out[(size_t)m * 512 + n] = acc[rb][cb][r];
      }
    }
}

// ---------------------------------------------------------------- launcher
// ws layout (bytes), total 253,493,248:
//   hb   bf16 [32768][512]            @ 0
//   Wc   bf16 [1536][512]             @ 33,554,432
//   Wob  bf16 [512][256]              @ 35,127,296
//   KQi  f32  [64][4096][64]          @ 35,389,440   (16 groups x [k0 k1 q0 q1])
//   AVB  f32x4 [64][4096][32]         @ 102,498,304  (a, v, beta, pad)
//   ctx2 bf16 [32768][256]            @ 236,716,032
// d_out reuse: ctx f32 [32768][256] @ 0; gate f32 [32768][256] @ +8388608 floats
// (both overwritten later by out_gemm); Sfin @ +16777216 floats.
extern "C" void kernel_launch(void* const* d_in, const int* in_sizes, int n_in,
                              void* d_out, int out_size, void* d_ws, size_t ws_size,
                              hipStream_t stream) {
  (void)in_sizes; (void)n_in; (void)out_size; (void)ws_size;
  const float* hidden  = (const float*)d_in[0];
  const float* state   = (const float*)d_in[1];
  const float* W_k     = (const float*)d_in[2];
  const float* W_v     = (const float*)d_in[3];
  const float* W_q     = (const float*)d_in[4];
  const float* W_beta  = (const float*)d_in[5];
  const float* b_beta  = (const float*)d_in[6];
  const float* W_alpha = (const float*)d_in[7];
  const float* b_alpha = (const float*)d_in[8];
  const float* W_out   = (const float*)d_in[9];
  const float* gate_W  = (const float*)d_in[10];
  const float* norm_w  = (const float*)d_in[11];
  float* out = (float*)d_out;

  char* ws = (char*)d_ws;
  unsigned short* hb  = (unsigned short*)(ws);
  unsigned short* Wc  = (unsigned short*)(ws + 33554432);
  unsigned short* Wob = (unsigned short*)(ws + 35127296);
  float* KQi  = (float*)(ws + 35389440);
  float* AVBf = (float*)(ws + 102498304);
  unsigned short* ctx2 = (unsigned short*)(ws + 236716032);
  float* ctx  = out;                 // fp32 scratch, overwritten by out_gemm
  float* gate = out + 8388608;       // fp32 scratch, overwritten by out_gemm
  float* Sfin = out + 16777216;      // final state output

  cvt_f32_bf16<<<2048, 256, 0, stream>>>(hidden, hb, M_TOK * HID / 4);
  cvt_f32_bf16<<<64, 256, 0, stream>>>(W_k,     Wc + 0 * 131072, 32768);
  cvt_f32_bf16<<<64, 256, 0, stream>>>(W_v,     Wc + 1 * 131072, 32768);
  cvt_f32_bf16<<<64, 256, 0, stream>>>(W_q,     Wc + 2 * 131072, 32768);
  cvt_f32_bf16<<<64, 256, 0, stream>>>(W_beta,  Wc + 3 * 131072, 32768);
  cvt_f32_bf16<<<64, 256, 0, stream>>>(W_alpha, Wc + 4 * 131072, 32768);
  cvt_f32_bf16<<<64, 256, 0, stream>>>(gate_W,  Wc + 5 * 131072, 32768);
  cvt_f32_bf16<<<64, 256, 0, stream>>>(W_out,   Wob, 32768);

  proj_gemm<<<dim3(256, 8), 256, 0, stream>>>(hb, Wc, b_beta, b_alpha, KQi, AVBf, gate);
  scan_kernel<<<512, 128, 0, stream>>>(KQi, (const float4*)AVBf, state, ctx, Sfin);
  rms_silu<<<8192, 256, 0, stream>>>(ctx, gate, norm_w, ctx2);
  out_gemm<<<dim3(256, 8), 256, 0, stream>>>(ctx2, Wob, out);
}